// Round 9
// baseline (320.974 us; speedup 1.0000x reference)
//
#include <hip/hip_runtime.h>
#include <hip/hip_fp16.h>
#include <type_traits>

// Buckets: 512 nodes each, up to 256 buckets (nn <= 131072).
#define NBK 256
#define BSHIFT 9
#define NPB 512

template <int N> struct alignas(4 * N) HVec { __half2 v[N]; };

typedef _Float16 half8 __attribute__((ext_vector_type(8)));
typedef float f32x4 __attribute__((ext_vector_type(4)));
typedef float f32x2 __attribute__((ext_vector_type(2)));
typedef int i32x4 __attribute__((ext_vector_type(4)));
typedef unsigned int u32;

// ---- A1: per-bucket edge histogram ----
__global__ __launch_bounds__(256) void histA_k(const int* __restrict__ dst, int ne,
                                               int* __restrict__ gcount) {
    __shared__ int h[NBK];
    for (int i = threadIdx.x; i < NBK; i += 256) h[i] = 0;
    __syncthreads();
    int e0 = blockIdx.x * 4096;
    int e1 = min(e0 + 4096, ne);
    for (int e = e0 + (int)threadIdx.x; e < e1; e += 256)
        atomicAdd(&h[dst[e] >> BSHIFT], 1);
    __syncthreads();
    for (int i = threadIdx.x; i < NBK; i += 256)
        if (h[i]) atomicAdd(&gcount[i], h[i]);
}

// ---- A2: exclusive scan of PADDED bucket sizes -> bases + cursors ----
__global__ __launch_bounds__(256) void scanB_k(const int* __restrict__ gcount,
                                               int* __restrict__ gbase,
                                               int* __restrict__ cursor) {
    __shared__ int sh[NBK];
    int t = threadIdx.x;
    int v = ((gcount[t] + 7) & ~7) + 7 * NPB;   // 8-aligned upper bound (per-node pad8)
    sh[t] = v;
    __syncthreads();
    for (int d = 1; d < NBK; d <<= 1) {
        int u = (t >= d) ? sh[t - d] : 0;
        __syncthreads();
        sh[t] += u;
        __syncthreads();
    }
    int ex = sh[t] - v;
    gbase[t] = ex;
    cursor[t] = ex;
}

// ---- A3: partition edges into bucket regions, packed (dst_local<<17)|src ----
__global__ __launch_bounds__(512) void partA_k(const int* __restrict__ src,
                                               const int* __restrict__ dst,
                                               int* __restrict__ cursor,
                                               int* __restrict__ bucketed, int ne) {
    constexpr int EPB = 8192;
    __shared__ int hist[NBK], lofs[NBK + 1], lcur[NBK], gbs[NBK], sc[NBK];
    __shared__ int stage[EPB];
    int t = threadIdx.x;
    int e0 = blockIdx.x * EPB;
    int e1 = min(e0 + EPB, ne);
    int cnt = e1 - e0;
    for (int i = t; i < NBK; i += 512) hist[i] = 0;
    __syncthreads();
    int sv[16], dv[16];
#pragma unroll
    for (int k = 0; k < 16; k++) {
        int e = e0 + t + k * 512;
        int s = 0, d = 0;
        if (e < e1) {
            s = src[e];
            d = dst[e];
            atomicAdd(&hist[d >> BSHIFT], 1);
        }
        sv[k] = s;
        dv[k] = d;
    }
    __syncthreads();
    if (t < NBK) sc[t] = hist[t];
    __syncthreads();
    for (int d = 1; d < NBK; d <<= 1) {
        int u = 0;
        if (t < NBK && t >= d) u = sc[t - d];
        __syncthreads();
        if (t < NBK) sc[t] += u;
        __syncthreads();
    }
    if (t < NBK) {
        int ex = sc[t] - hist[t];
        lofs[t] = ex;
        lcur[t] = ex;
        gbs[t] = hist[t] ? atomicAdd(&cursor[t], hist[t]) : 0;
    }
    if (t == 0) lofs[NBK] = cnt;
    __syncthreads();
#pragma unroll
    for (int k = 0; k < 16; k++) {
        int e = e0 + t + k * 512;
        if (e < e1) {
            int b = dv[k] >> BSHIFT;
            int q = atomicAdd(&lcur[b], 1);
            stage[q] = ((dv[k] & (NPB - 1)) << 17) | sv[k];
        }
    }
    __syncthreads();
    for (int idx = t; idx < cnt; idx += 512) {
        int lo = 0, hi = NBK;
        while (hi - lo > 1) {
            int mid = (lo + hi) >> 1;
            if (lofs[mid] <= idx) lo = mid; else hi = mid;
        }
        bucketed[gbs[lo] + (idx - lofs[lo])] = stage[idx];
    }
}

// ---- B: per-bucket CSR finalize with per-node pad8 (dummy src = nn -> zero row) ----
__global__ __launch_bounds__(1024) void csrB_k(const int* __restrict__ bucketed,
                                               const int* __restrict__ gbase,
                                               const int* __restrict__ gcount,
                                               int* __restrict__ csr,
                                               int* __restrict__ rowbeg,
                                               int* __restrict__ rend,
                                               float* __restrict__ dinv, int nn) {
    constexpr int CAP = 12288;
    __shared__ int cnt[NPB], ofs[NPB], cur[NPB];
    __shared__ int stage[CAP];
    __shared__ int ptot_s;
    int t = threadIdx.x;
    int b = blockIdx.x;
    int beg = gbase[b];
    int m = gcount[b];
    if (t < NPB) cnt[t] = 0;
    __syncthreads();
    for (int i = t; i < m; i += 1024)
        atomicAdd(&cnt[bucketed[beg + i] >> 17], 1);
    __syncthreads();
    int v = 0, pv = 0;
    if (t < NPB) { v = cnt[t]; pv = (v + 7) & ~7; ofs[t] = pv; }
    __syncthreads();
    for (int d = 1; d < NPB; d <<= 1) {
        int u = 0;
        if (t < NPB && t >= d) u = ofs[t - d];
        __syncthreads();
        if (t < NPB) ofs[t] += u;
        __syncthreads();
    }
    if (t == NPB - 1) ptot_s = ofs[t];
    int ex = 0;
    if (t < NPB) {
        ex = ofs[t] - pv;
        cur[t] = ex;
        int node = b * NPB + t;
        if (node < nn) {
            rowbeg[node] = beg + ex;
            rend[node]   = beg + ex + pv;
            dinv[node] = rsqrtf((float)(v + 1));   // +1 self-loop
        }
    }
    __syncthreads();
    int ptot = ptot_s;
    if (ptot <= CAP) {
        for (int i = t; i < m; i += 1024) {
            int e = bucketed[beg + i];
            int p = atomicAdd(&cur[e >> 17], 1);
            stage[p] = e & 0x1FFFF;
        }
        __syncthreads();
        if (t < NPB)
            for (int k = v; k < pv; k++) stage[ex + k] = nn;   // dummy pads
        __syncthreads();
        for (int i = t; i < ptot; i += 1024) csr[beg + i] = stage[i];
    } else {  // defensive fallback
        for (int i = t; i < m; i += 1024) {
            int e = bucketed[beg + i];
            int p = atomicAdd(&cur[e >> 17], 1);
            csr[beg + p] = e & 0x1FFFF;
        }
        __syncthreads();
        if (t < NPB)
            for (int k = v; k < pv; k++) csr[beg + ex + k] = nn;
    }
}

// ---- W prep: transpose+fp16 WT1/WT2; zero the 8 dummy rows hC[c][nn][:] ----
__global__ void prepW_k(const float* __restrict__ W1, const float* __restrict__ W2,
                        _Float16* __restrict__ WT1, _Float16* __restrict__ WT2,
                        _Float16* __restrict__ hC, int nn) {
    int i = blockIdx.x * blockDim.x + threadIdx.x;
    if (i < 128 * 128) {
        int k = i >> 7, j = i & 127;
        WT1[j * 128 + k] = (_Float16)W1[i];
    }
    int i2 = i - 128 * 128;
    if (i2 >= 0 && i2 < 128 * 64) {
        int k = i2 >> 6, j = i2 & 63;
        WT2[j * 128 + k] = (_Float16)W2[i2];
    }
    int i3 = i - (128 * 128 + 128 * 64);
    if (i3 >= 0 && i3 < 8 * 16) {
        int c = i3 >> 4, j = i3 & 15;
        hC[(size_t)c * ((size_t)(nn + 1) * 16) + (size_t)nn * 16 + j] = (_Float16)0.f;
    }
}

// ---------------- MFMA dense transform: H = X @ W, CHUNKED output ----------------
template <int NO, bool SCALE, typename XT>
__global__ __launch_bounds__(256) void gemm_mfma_k(const XT* __restrict__ X,
                                                   const _Float16* __restrict__ WT,
                                                   const float* __restrict__ dinv,
                                                   _Float16* __restrict__ H, int nrows) {
    constexpr int K = 128;
    constexpr int NCT = NO / 16;
    int wv = (int)((blockIdx.x * (size_t)blockDim.x + threadIdx.x) >> 6);
    int r0 = wv * 16;
    if (r0 >= nrows) return;
    int lane = threadIdx.x & 63;
    int lr = lane & 15;          // A-row / D-col
    int kg = lane >> 4;          // k-group
    int rg = r0 + lr;
    if (rg >= nrows) rg = nrows - 1;   // clamp (stores are guarded)
    size_t cs = (size_t)(nrows + 1) * 16;    // chunk stride (incl. dummy row)

    half8 a[4];
    if constexpr (std::is_same<XT, float>::value) {
#pragma unroll
        for (int ks = 0; ks < 4; ks++) {
            const float* px = X + (size_t)rg * K + ks * 32 + kg * 8;
            float4 x0 = *(const float4*)px;
            float4 x1 = *(const float4*)(px + 4);
            half8 vv;
            vv[0] = (_Float16)x0.x; vv[1] = (_Float16)x0.y;
            vv[2] = (_Float16)x0.z; vv[3] = (_Float16)x0.w;
            vv[4] = (_Float16)x1.x; vv[5] = (_Float16)x1.y;
            vv[6] = (_Float16)x1.z; vv[7] = (_Float16)x1.w;
            a[ks] = vv;
        }
    } else {
#pragma unroll
        for (int ks = 0; ks < 4; ks++)
            a[ks] = *(const half8*)(X + (size_t)rg * K + ks * 32 + kg * 8);
    }

    f32x4 acc[NCT];
#pragma unroll
    for (int ct = 0; ct < NCT; ct++) acc[ct] = (f32x4){0.f, 0.f, 0.f, 0.f};
#pragma unroll
    for (int ct = 0; ct < NCT; ct++) {
#pragma unroll
        for (int ks = 0; ks < 4; ks++) {
            half8 b = *(const half8*)(WT + (size_t)(ct * 16 + lr) * K + ks * 32 + kg * 8);
            acc[ct] = __builtin_amdgcn_mfma_f32_16x16x32_f16(a[ks], b, acc[ct], 0, 0, 0);
        }
    }
#pragma unroll
    for (int i = 0; i < 4; i++) {
        int rr = r0 + kg * 4 + i;
        if (rr < nrows) {
            float s = SCALE ? dinv[rr] : 1.f;
            _Float16* hp = H + (size_t)rr * 16 + lr;
#pragma unroll
            for (int ct = 0; ct < NCT; ct++)
                hp[ct * cs] = (_Float16)(acc[ct][i] * s);
        }
    }
}

// ---------------- chunked aggregation v4: group-per-node + deep pipeline ----------------
// Same layout as v3 (HC[c][node][16], chunk=blockIdx%NCHUNK -> XCD L2 slice), but:
//  - edge loop unrolled 8x (pad8 CSR segments): 8 gathers in flight per group
//  - csr software-pipelined: next 8 indices loaded before consuming current gathers
//  - csr/rowbeg/rend nontemporal (don't evict the h-slice from L2)
//  - outputs nontemporal (write-once, no write-allocate pollution)
template <int NF, int NCHUNK, bool RELU, bool OUTSCALE, typename OutT>
__global__ __launch_bounds__(256) void aggc4_k(const __half* __restrict__ HC,
                                               const int* __restrict__ rowbeg,
                                               const int* __restrict__ rend,
                                               const int* __restrict__ csr,
                                               const float* __restrict__ dinv,
                                               const float* __restrict__ bias,
                                               OutT* __restrict__ Out, int nn) {
    constexpr int CF = 16;
    int chunk = (int)(blockIdx.x % NCHUNK);
    int ngrp = (int)(blockIdx.x / NCHUNK);
    int t = threadIdx.x;
    int li = t & 7;                  // feature-pair index within node group
    int nid = ngrp * 32 + (t >> 3);  // 32 nodes per block (8 per wave)
    if (nid >= nn) return;
    const __half* Hc = HC + (size_t)chunk * ((size_t)(nn + 1) * CF) + li * 2;

    float ax = 0.f, ay = 0.f;
    int i = __builtin_nontemporal_load(rowbeg + nid);
    int end = __builtin_nontemporal_load(rend + nid);

    auto acc8 = [&](i32x4 c0, i32x4 c1) {
        __half2 v0 = *(const __half2*)(Hc + (size_t)c0.x * CF);
        __half2 v1 = *(const __half2*)(Hc + (size_t)c0.y * CF);
        __half2 v2 = *(const __half2*)(Hc + (size_t)c0.z * CF);
        __half2 v3 = *(const __half2*)(Hc + (size_t)c0.w * CF);
        __half2 v4 = *(const __half2*)(Hc + (size_t)c1.x * CF);
        __half2 v5 = *(const __half2*)(Hc + (size_t)c1.y * CF);
        __half2 v6 = *(const __half2*)(Hc + (size_t)c1.z * CF);
        __half2 v7 = *(const __half2*)(Hc + (size_t)c1.w * CF);
        __half2 p01 = __hadd2(v0, v1);      // fp16 tree, 2 levels
        __half2 p23 = __hadd2(v2, v3);
        __half2 p45 = __hadd2(v4, v5);
        __half2 p67 = __hadd2(v6, v7);
        __half2 q0 = __hadd2(p01, p23);
        __half2 q1 = __hadd2(p45, p67);
        float2 f0 = __half22float2(q0);
        float2 f1 = __half22float2(q1);
        ax += f0.x + f1.x;
        ay += f0.y + f1.y;
    };

    if (i < end) {
        i32x4 c0 = __builtin_nontemporal_load((const i32x4*)(csr + i));
        i32x4 c1 = __builtin_nontemporal_load((const i32x4*)(csr + i + 4));
        for (i += 8; i < end; i += 8) {
            i32x4 n0 = __builtin_nontemporal_load((const i32x4*)(csr + i));
            i32x4 n1 = __builtin_nontemporal_load((const i32x4*)(csr + i + 4));
            acc8(c0, c1);
            c0 = n0; c1 = n1;
        }
        acc8(c0, c1);
    }

    // self-loop (h'[nid], already dinv-scaled)
    __half2 hs = *(const __half2*)(Hc + (size_t)nid * CF);
    float2 fs = __half22float2(hs);
    float dn = dinv[nid];
    const float2 b2v = *(const float2*)(bias + chunk * CF + li * 2);
    float rx = (ax + fs.x) * dn + b2v.x;
    float ry = (ay + fs.y) * dn + b2v.y;
    if (RELU) { rx = fmaxf(rx, 0.f); ry = fmaxf(ry, 0.f); }
    if (OUTSCALE) { rx *= dn; ry *= dn; }
    if constexpr (std::is_same<OutT, __half>::value) {
        __half2 o = __floats2half2_rn(rx, ry);
        u32 ou;
        __builtin_memcpy(&ou, &o, 4);
        __builtin_nontemporal_store(ou, (u32*)(Out + (size_t)nid * NF + chunk * CF + li * 2));
    } else {
        f32x2 o = {rx, ry};
        __builtin_nontemporal_store(o, (f32x2*)(Out + (size_t)nid * NF + chunk * CF + li * 2));
    }
}

// ---------------- launch ----------------

extern "C" void kernel_launch(void* const* d_in, const int* in_sizes, int n_in,
                              void* d_out, int out_size, void* d_ws, size_t ws_size,
                              hipStream_t stream) {
    const float* x  = (const float*)d_in[0];
    const int* ei   = (const int*)d_in[1];
    const float* W1 = (const float*)d_in[2];
    const float* b1 = (const float*)d_in[3];
    const float* W2 = (const float*)d_in[4];
    const float* b2 = (const float*)d_in[5];
    float* out = (float*)d_out;

    const int IN = 128, HID = 128;
    int nn = in_sizes[0] / IN;     // 100000
    int ne = in_sizes[1] / 2;      // 1600000
    const int* src = ei;
    const int* dst = ei + ne;
    int nbuckets = (nn + NPB - 1) / NPB;   // 196 (<= NBK)

    char* w = (char*)d_ws;
    size_t off = 0;
    auto take = [&](size_t bytes) -> void* {
        void* p = w + off;
        off = (off + bytes + 255) & ~(size_t)255;
        return p;
    };
    int*      gcount = (int*)take(NBK * 4);
    int*      gbase  = (int*)take(NBK * 4);
    int*      cursor = (int*)take(NBK * 4);
    int*      rowbeg = (int*)take((size_t)nn * 4);
    int*      rend   = (int*)take((size_t)nn * 4);
    float*    dinv   = (float*)take((size_t)nn * 4);
    int*      csr    = (int*)take(((size_t)ne + (size_t)NBK * 3600) * 4);   // pad8 CSR
    _Float16* WT1    = (_Float16*)take(128 * 128 * 2);
    _Float16* WT2    = (_Float16*)take(64 * 128 * 2);
    _Float16* hC     = (_Float16*)take((size_t)(nn + 1) * 128 * 2); // 8 x [nn+1][16]
    __half*   h1     = (__half*)take((size_t)nn * HID * 2);         // row-major
    _Float16* h2C    = hC;                 // reuse: hC dead after agg1 (4 x [nn+1][16])
    int*      bucketed = (int*)hC;         // reuse: dead before prepW/gemm1 touch hC

    (void)ws_size; (void)n_in; (void)out_size;

    hipMemsetAsync(gcount, 0, NBK * 4, stream);

    int tb = 256;
    histA_k<<<(ne + 4095) / 4096, 256, 0, stream>>>(dst, ne, gcount);
    scanB_k<<<1, NBK, 0, stream>>>(gcount, gbase, cursor);
    partA_k<<<(ne + 8191) / 8192, 512, 0, stream>>>(src, dst, cursor, bucketed, ne);
    csrB_k<<<nbuckets, 1024, 0, stream>>>(bucketed, gbase, gcount, csr, rowbeg, rend, dinv, nn);
    prepW_k<<<(128 * 128 + 128 * 64 + 128 + tb - 1) / tb, tb, 0, stream>>>(W1, W2, WT1, WT2, hC, nn);

    int gblocks = ((nn + 15) / 16 + 3) / 4;   // 1 wave per 16 rows, 4 waves/block
    int ngrp32 = (nn + 31) / 32;              // node groups of 32 for aggc4

    // layer 1: hC = dinv .* (x @ W1)  [fp16, chunked] ; h1 = dinv .* relu(agg(hC) + b1)
    gemm_mfma_k<128, true, float><<<gblocks, tb, 0, stream>>>(x, WT1, dinv, hC, nn);
    aggc4_k<128, 8, true, true, __half><<<ngrp32 * 8, tb, 0, stream>>>(
        (const __half*)hC, rowbeg, rend, csr, dinv, b1, h1, nn);

    // layer 2: h2C = h1 @ W2 (already dinv-scaled)  [chunked] ; out = agg(h2C) + b2  [fp32]
    gemm_mfma_k<64, false, __half><<<gblocks, tb, 0, stream>>>(h1, WT2, dinv, h2C, nn);
    aggc4_k<64, 4, false, false, float><<<ngrp32 * 4, tb, 0, stream>>>(
        (const __half*)h2C, rowbeg, rend, csr, dinv, b2, out, nn);
}

// Round 10
// 236.634 us; speedup vs baseline: 1.3564x; 1.3564x over previous
//
#include <hip/hip_runtime.h>
#include <hip/hip_fp16.h>
#include <type_traits>

// Buckets: 512 nodes each, up to 256 buckets (nn <= 131072).
#define NBK 256
#define BSHIFT 9
#define NPB 512

template <int N> struct alignas(4 * N) HVec { __half2 v[N]; };

typedef _Float16 half8 __attribute__((ext_vector_type(8)));
typedef float f32x4 __attribute__((ext_vector_type(4)));

// ---- A1: per-bucket edge histogram ----
__global__ __launch_bounds__(256) void histA_k(const int* __restrict__ dst, int ne,
                                               int* __restrict__ gcount) {
    __shared__ int h[NBK];
    for (int i = threadIdx.x; i < NBK; i += 256) h[i] = 0;
    __syncthreads();
    int e0 = blockIdx.x * 4096;
    int e1 = min(e0 + 4096, ne);
    for (int e = e0 + (int)threadIdx.x; e < e1; e += 256)
        atomicAdd(&h[dst[e] >> BSHIFT], 1);
    __syncthreads();
    for (int i = threadIdx.x; i < NBK; i += 256)
        if (h[i]) atomicAdd(&gcount[i], h[i]);
}

// ---- A2: exclusive scan of PADDED bucket sizes -> bases + cursors ----
__global__ __launch_bounds__(256) void scanB_k(const int* __restrict__ gcount,
                                               int* __restrict__ gbase,
                                               int* __restrict__ cursor) {
    __shared__ int sh[NBK];
    int t = threadIdx.x;
    int v = ((gcount[t] + 7) & ~7) + 7 * NPB;   // 8-aligned upper bound (per-node pad8)
    sh[t] = v;
    __syncthreads();
    for (int d = 1; d < NBK; d <<= 1) {
        int u = (t >= d) ? sh[t - d] : 0;
        __syncthreads();
        sh[t] += u;
        __syncthreads();
    }
    int ex = sh[t] - v;
    gbase[t] = ex;
    cursor[t] = ex;
}

// ---- A3: partition edges into bucket regions, packed (dst_local<<17)|src ----
__global__ __launch_bounds__(512) void partA_k(const int* __restrict__ src,
                                               const int* __restrict__ dst,
                                               int* __restrict__ cursor,
                                               int* __restrict__ bucketed, int ne) {
    constexpr int EPB = 8192;
    __shared__ int hist[NBK], lofs[NBK + 1], lcur[NBK], gbs[NBK], sc[NBK];
    __shared__ int stage[EPB];
    int t = threadIdx.x;
    int e0 = blockIdx.x * EPB;
    int e1 = min(e0 + EPB, ne);
    int cnt = e1 - e0;
    for (int i = t; i < NBK; i += 512) hist[i] = 0;
    __syncthreads();
    int sv[16], dv[16];
#pragma unroll
    for (int k = 0; k < 16; k++) {
        int e = e0 + t + k * 512;
        int s = 0, d = 0;
        if (e < e1) {
            s = src[e];
            d = dst[e];
            atomicAdd(&hist[d >> BSHIFT], 1);
        }
        sv[k] = s;
        dv[k] = d;
    }
    __syncthreads();
    if (t < NBK) sc[t] = hist[t];
    __syncthreads();
    for (int d = 1; d < NBK; d <<= 1) {
        int u = 0;
        if (t < NBK && t >= d) u = sc[t - d];
        __syncthreads();
        if (t < NBK) sc[t] += u;
        __syncthreads();
    }
    if (t < NBK) {
        int ex = sc[t] - hist[t];
        lofs[t] = ex;
        lcur[t] = ex;
        gbs[t] = hist[t] ? atomicAdd(&cursor[t], hist[t]) : 0;
    }
    if (t == 0) lofs[NBK] = cnt;
    __syncthreads();
#pragma unroll
    for (int k = 0; k < 16; k++) {
        int e = e0 + t + k * 512;
        if (e < e1) {
            int b = dv[k] >> BSHIFT;
            int q = atomicAdd(&lcur[b], 1);
            stage[q] = ((dv[k] & (NPB - 1)) << 17) | sv[k];
        }
    }
    __syncthreads();
    for (int idx = t; idx < cnt; idx += 512) {
        int lo = 0, hi = NBK;
        while (hi - lo > 1) {
            int mid = (lo + hi) >> 1;
            if (lofs[mid] <= idx) lo = mid; else hi = mid;
        }
        bucketed[gbs[lo] + (idx - lofs[lo])] = stage[idx];
    }
}

// ---- B: per-bucket CSR finalize with per-node pad8 (dummy src = nn -> zero row) ----
__global__ __launch_bounds__(1024) void csrB_k(const int* __restrict__ bucketed,
                                               const int* __restrict__ gbase,
                                               const int* __restrict__ gcount,
                                               int* __restrict__ csr,
                                               int* __restrict__ rowbeg,
                                               int* __restrict__ rend,
                                               float* __restrict__ dinv, int nn) {
    constexpr int CAP = 12288;
    __shared__ int cnt[NPB], ofs[NPB], cur[NPB];
    __shared__ int stage[CAP];
    __shared__ int ptot_s;
    int t = threadIdx.x;
    int b = blockIdx.x;
    int beg = gbase[b];
    int m = gcount[b];
    if (t < NPB) cnt[t] = 0;
    __syncthreads();
    for (int i = t; i < m; i += 1024)
        atomicAdd(&cnt[bucketed[beg + i] >> 17], 1);
    __syncthreads();
    int v = 0, pv = 0;
    if (t < NPB) { v = cnt[t]; pv = (v + 7) & ~7; ofs[t] = pv; }
    __syncthreads();
    for (int d = 1; d < NPB; d <<= 1) {
        int u = 0;
        if (t < NPB && t >= d) u = ofs[t - d];
        __syncthreads();
        if (t < NPB) ofs[t] += u;
        __syncthreads();
    }
    if (t == NPB - 1) ptot_s = ofs[t];
    int ex = 0;
    if (t < NPB) {
        ex = ofs[t] - pv;
        cur[t] = ex;
        int node = b * NPB + t;
        if (node < nn) {
            rowbeg[node] = beg + ex;
            rend[node]   = beg + ex + pv;
            dinv[node] = rsqrtf((float)(v + 1));   // +1 self-loop
        }
    }
    __syncthreads();
    int ptot = ptot_s;
    if (ptot <= CAP) {
        for (int i = t; i < m; i += 1024) {
            int e = bucketed[beg + i];
            int p = atomicAdd(&cur[e >> 17], 1);
            stage[p] = e & 0x1FFFF;
        }
        __syncthreads();
        if (t < NPB)
            for (int k = v; k < pv; k++) stage[ex + k] = nn;   // dummy pads
        __syncthreads();
        for (int i = t; i < ptot; i += 1024) csr[beg + i] = stage[i];
    } else {  // defensive fallback
        for (int i = t; i < m; i += 1024) {
            int e = bucketed[beg + i];
            int p = atomicAdd(&cur[e >> 17], 1);
            csr[beg + p] = e & 0x1FFFF;
        }
        __syncthreads();
        if (t < NPB)
            for (int k = v; k < pv; k++) csr[beg + ex + k] = nn;
    }
}

// ---- W prep: transpose+fp16 WT1/WT2; zero the 8 dummy rows hC[c][nn][:] ----
__global__ void prepW_k(const float* __restrict__ W1, const float* __restrict__ W2,
                        _Float16* __restrict__ WT1, _Float16* __restrict__ WT2,
                        _Float16* __restrict__ hC, int nn) {
    int i = blockIdx.x * blockDim.x + threadIdx.x;
    if (i < 128 * 128) {
        int k = i >> 7, j = i & 127;
        WT1[j * 128 + k] = (_Float16)W1[i];
    }
    int i2 = i - 128 * 128;
    if (i2 >= 0 && i2 < 128 * 64) {
        int k = i2 >> 6, j = i2 & 63;
        WT2[j * 128 + k] = (_Float16)W2[i2];
    }
    int i3 = i - (128 * 128 + 128 * 64);
    if (i3 >= 0 && i3 < 8 * 16) {
        int c = i3 >> 4, j = i3 & 15;
        hC[(size_t)c * ((size_t)(nn + 1) * 16) + (size_t)nn * 16 + j] = (_Float16)0.f;
    }
}

// ---------------- MFMA dense transform: H = X @ W, CHUNKED output ----------------
template <int NO, bool SCALE, typename XT>
__global__ __launch_bounds__(256) void gemm_mfma_k(const XT* __restrict__ X,
                                                   const _Float16* __restrict__ WT,
                                                   const float* __restrict__ dinv,
                                                   _Float16* __restrict__ H, int nrows) {
    constexpr int K = 128;
    constexpr int NCT = NO / 16;
    int wv = (int)((blockIdx.x * (size_t)blockDim.x + threadIdx.x) >> 6);
    int r0 = wv * 16;
    if (r0 >= nrows) return;
    int lane = threadIdx.x & 63;
    int lr = lane & 15;          // A-row / D-col
    int kg = lane >> 4;          // k-group
    int rg = r0 + lr;
    if (rg >= nrows) rg = nrows - 1;   // clamp (stores are guarded)
    size_t cs = (size_t)(nrows + 1) * 16;    // chunk stride (incl. dummy row)

    half8 a[4];
    if constexpr (std::is_same<XT, float>::value) {
#pragma unroll
        for (int ks = 0; ks < 4; ks++) {
            const float* px = X + (size_t)rg * K + ks * 32 + kg * 8;
            float4 x0 = *(const float4*)px;
            float4 x1 = *(const float4*)(px + 4);
            half8 vv;
            vv[0] = (_Float16)x0.x; vv[1] = (_Float16)x0.y;
            vv[2] = (_Float16)x0.z; vv[3] = (_Float16)x0.w;
            vv[4] = (_Float16)x1.x; vv[5] = (_Float16)x1.y;
            vv[6] = (_Float16)x1.z; vv[7] = (_Float16)x1.w;
            a[ks] = vv;
        }
    } else {
#pragma unroll
        for (int ks = 0; ks < 4; ks++)
            a[ks] = *(const half8*)(X + (size_t)rg * K + ks * 32 + kg * 8);
    }

    f32x4 acc[NCT];
#pragma unroll
    for (int ct = 0; ct < NCT; ct++) acc[ct] = (f32x4){0.f, 0.f, 0.f, 0.f};
#pragma unroll
    for (int ct = 0; ct < NCT; ct++) {
#pragma unroll
        for (int ks = 0; ks < 4; ks++) {
            half8 b = *(const half8*)(WT + (size_t)(ct * 16 + lr) * K + ks * 32 + kg * 8);
            acc[ct] = __builtin_amdgcn_mfma_f32_16x16x32_f16(a[ks], b, acc[ct], 0, 0, 0);
        }
    }
#pragma unroll
    for (int i = 0; i < 4; i++) {
        int rr = r0 + kg * 4 + i;
        if (rr < nrows) {
            float s = SCALE ? dinv[rr] : 1.f;
            _Float16* hp = H + (size_t)rr * 16 + lr;
#pragma unroll
            for (int ct = 0; ct < NCT; ct++)
                hp[ct * cs] = (_Float16)(acc[ct][i] * s);
        }
    }
}

// ---------------- chunked aggregation v5: 16B/lane gathers + slot reduction ----------------
// HC[c][node][16] fp16 (32B rows), slice 3.2MB -> XCD-L2-resident via chunk=blockIdx%NCHUNK.
// Wave = 8 nodes x 8 lanes; node's lanes = 4 edge-slots x 2 half-rows. Each lane gathers a
// FULL 16B half-row (16B/address, 4x fewer addresses than v3/v4). Edge loop does 2 edges/lane
// per iter (pad8 segments, explicit csr pipeline, PLAIN loads - nt reverted). Slot reduction
// (2 shfl_xor levels) happens once per node at the end, not per edge.
template <int NF, int NCHUNK, bool RELU, bool OUTSCALE, typename OutT>
__global__ __launch_bounds__(256) void aggc5_k(const __half* __restrict__ HC,
                                               const int* __restrict__ rowbeg,
                                               const int* __restrict__ rend,
                                               const int* __restrict__ csr,
                                               const float* __restrict__ dinv,
                                               const float* __restrict__ bias,
                                               OutT* __restrict__ Out, int nn) {
    constexpr int CF = 16;
    int chunk = (int)(blockIdx.x % NCHUNK);
    int ngrp = (int)(blockIdx.x / NCHUNK);
    int t = threadIdx.x;
    int half = t & 1;                 // half-row (8 features, 16B)
    int slot = (t >> 1) & 3;          // edge slot
    int nid = ngrp * 32 + (t >> 3);   // 32 nodes per block (8 per wave)
    if (nid >= nn) return;
    const __half* Hc = HC + (size_t)chunk * ((size_t)(nn + 1) * CF) + half * 8;

    float acc[8];
#pragma unroll
    for (int j = 0; j < 8; j++) acc[j] = 0.f;

    int i = rowbeg[nid], end = rend[nid];
    if (i < end) {
        int e0 = csr[i + slot];           // coalesced: 8 lanes read 4 ints
        int e1 = csr[i + 4 + slot];
        for (i += 8; i < end; i += 8) {
            int n0 = csr[i + slot];       // pipeline: next indices before consuming
            int n1 = csr[i + 4 + slot];
            HVec<4> va = *(const HVec<4>*)(Hc + (size_t)e0 * CF);
            HVec<4> vb = *(const HVec<4>*)(Hc + (size_t)e1 * CF);
#pragma unroll
            for (int q = 0; q < 4; q++) {
                __half2 p = __hadd2(va.v[q], vb.v[q]);   // one fp16 pair-add level
                float2 f = __half22float2(p);
                acc[2 * q + 0] += f.x;
                acc[2 * q + 1] += f.y;
            }
            e0 = n0; e1 = n1;
        }
        HVec<4> va = *(const HVec<4>*)(Hc + (size_t)e0 * CF);
        HVec<4> vb = *(const HVec<4>*)(Hc + (size_t)e1 * CF);
#pragma unroll
        for (int q = 0; q < 4; q++) {
            __half2 p = __hadd2(va.v[q], vb.v[q]);
            float2 f = __half22float2(p);
            acc[2 * q + 0] += f.x;
            acc[2 * q + 1] += f.y;
        }
    }
    // reduce over the 4 slots (lane bits 1..2) - once per node
#pragma unroll
    for (int j = 0; j < 8; j++) {
        acc[j] += __shfl_xor(acc[j], 2);
        acc[j] += __shfl_xor(acc[j], 4);
    }
    if (slot == 0) {
        // self-loop (h'[nid], already dinv-scaled)
        HVec<4> hs = *(const HVec<4>*)(Hc + (size_t)nid * CF);
        float dn = dinv[nid];
        const float4 b0 = *(const float4*)(bias + chunk * CF + half * 8);
        const float4 b1 = *(const float4*)(bias + chunk * CF + half * 8 + 4);
        float bb[8] = {b0.x, b0.y, b0.z, b0.w, b1.x, b1.y, b1.z, b1.w};
        float r[8];
#pragma unroll
        for (int q = 0; q < 4; q++) {
            float2 f = __half22float2(hs.v[q]);
            r[2 * q + 0] = (acc[2 * q + 0] + f.x) * dn + bb[2 * q + 0];
            r[2 * q + 1] = (acc[2 * q + 1] + f.y) * dn + bb[2 * q + 1];
        }
#pragma unroll
        for (int j = 0; j < 8; j++) {
            if (RELU) r[j] = fmaxf(r[j], 0.f);
            if (OUTSCALE) r[j] *= dn;      // pre-scale for next layer's aggregation
        }
        if constexpr (std::is_same<OutT, __half>::value) {
            HVec<4> o;
#pragma unroll
            for (int q = 0; q < 4; q++) o.v[q] = __floats2half2_rn(r[2 * q], r[2 * q + 1]);
            *(HVec<4>*)(Out + (size_t)nid * NF + chunk * CF + half * 8) = o;  // row-major
        } else {
            float* op = Out + (size_t)nid * NF + chunk * CF + half * 8;
            float4 o0, o1;
            o0.x = r[0]; o0.y = r[1]; o0.z = r[2]; o0.w = r[3];
            o1.x = r[4]; o1.y = r[5]; o1.z = r[6]; o1.w = r[7];
            *(float4*)op = o0;
            *(float4*)(op + 4) = o1;
        }
    }
}

// ---------------- launch ----------------

extern "C" void kernel_launch(void* const* d_in, const int* in_sizes, int n_in,
                              void* d_out, int out_size, void* d_ws, size_t ws_size,
                              hipStream_t stream) {
    const float* x  = (const float*)d_in[0];
    const int* ei   = (const int*)d_in[1];
    const float* W1 = (const float*)d_in[2];
    const float* b1 = (const float*)d_in[3];
    const float* W2 = (const float*)d_in[4];
    const float* b2 = (const float*)d_in[5];
    float* out = (float*)d_out;

    const int IN = 128, HID = 128;
    int nn = in_sizes[0] / IN;     // 100000
    int ne = in_sizes[1] / 2;      // 1600000
    const int* src = ei;
    const int* dst = ei + ne;
    int nbuckets = (nn + NPB - 1) / NPB;   // 196 (<= NBK)

    char* w = (char*)d_ws;
    size_t off = 0;
    auto take = [&](size_t bytes) -> void* {
        void* p = w + off;
        off = (off + bytes + 255) & ~(size_t)255;
        return p;
    };
    int*      gcount = (int*)take(NBK * 4);
    int*      gbase  = (int*)take(NBK * 4);
    int*      cursor = (int*)take(NBK * 4);
    int*      rowbeg = (int*)take((size_t)nn * 4);
    int*      rend   = (int*)take((size_t)nn * 4);
    float*    dinv   = (float*)take((size_t)nn * 4);
    int*      csr    = (int*)take(((size_t)ne + (size_t)NBK * 3600) * 4);   // pad8 CSR
    _Float16* WT1    = (_Float16*)take(128 * 128 * 2);
    _Float16* WT2    = (_Float16*)take(64 * 128 * 2);
    _Float16* hC     = (_Float16*)take((size_t)(nn + 1) * 128 * 2); // 8 x [nn+1][16]
    __half*   h1     = (__half*)take((size_t)nn * HID * 2);         // row-major
    _Float16* h2C    = hC;                 // reuse: hC dead after agg1 (4 x [nn+1][16])
    int*      bucketed = (int*)hC;         // reuse: dead before prepW/gemm1 touch hC

    (void)ws_size; (void)n_in; (void)out_size;

    hipMemsetAsync(gcount, 0, NBK * 4, stream);

    int tb = 256;
    histA_k<<<(ne + 4095) / 4096, 256, 0, stream>>>(dst, ne, gcount);
    scanB_k<<<1, NBK, 0, stream>>>(gcount, gbase, cursor);
    partA_k<<<(ne + 8191) / 8192, 512, 0, stream>>>(src, dst, cursor, bucketed, ne);
    csrB_k<<<nbuckets, 1024, 0, stream>>>(bucketed, gbase, gcount, csr, rowbeg, rend, dinv, nn);
    prepW_k<<<(128 * 128 + 128 * 64 + 128 + tb - 1) / tb, tb, 0, stream>>>(W1, W2, WT1, WT2, hC, nn);

    int gblocks = ((nn + 15) / 16 + 3) / 4;   // 1 wave per 16 rows, 4 waves/block
    int ngrp32 = (nn + 31) / 32;              // node groups of 32 for aggc5

    // layer 1: hC = dinv .* (x @ W1)  [fp16, chunked] ; h1 = dinv .* relu(agg(hC) + b1)
    gemm_mfma_k<128, true, float><<<gblocks, tb, 0, stream>>>(x, WT1, dinv, hC, nn);
    aggc5_k<128, 8, true, true, __half><<<ngrp32 * 8, tb, 0, stream>>>(
        (const __half*)hC, rowbeg, rend, csr, dinv, b1, h1, nn);

    // layer 2: h2C = h1 @ W2 (already dinv-scaled)  [chunked] ; out = agg(h2C) + b2  [fp32]
    gemm_mfma_k<64, false, __half><<<gblocks, tb, 0, stream>>>(h1, WT2, dinv, h2C, nn);
    aggc5_k<64, 4, false, false, float><<<ngrp32 * 4, tb, 0, stream>>>(
        (const __half*)h2C, rowbeg, rend, csr, dinv, b2, out, nn);
}

// Round 11
// 216.675 us; speedup vs baseline: 1.4814x; 1.0921x over previous
//
#include <hip/hip_runtime.h>
#include <hip/hip_fp16.h>
#include <type_traits>

// Buckets: 512 nodes each, up to 256 buckets (nn <= 131072).
#define NBK 256
#define BSHIFT 9
#define NPB 512

template <int N> struct alignas(4 * N) HVec { __half2 v[N]; };

typedef _Float16 half8 __attribute__((ext_vector_type(8)));
typedef float f32x4 __attribute__((ext_vector_type(4)));

// ---- A1: per-bucket edge histogram ----
__global__ __launch_bounds__(256) void histA_k(const int* __restrict__ dst, int ne,
                                               int* __restrict__ gcount) {
    __shared__ int h[NBK];
    for (int i = threadIdx.x; i < NBK; i += 256) h[i] = 0;
    __syncthreads();
    int e0 = blockIdx.x * 4096;
    int e1 = min(e0 + 4096, ne);
    for (int e = e0 + (int)threadIdx.x; e < e1; e += 256)
        atomicAdd(&h[dst[e] >> BSHIFT], 1);
    __syncthreads();
    for (int i = threadIdx.x; i < NBK; i += 256)
        if (h[i]) atomicAdd(&gcount[i], h[i]);
}

// ---- A2: exclusive scan of PADDED bucket sizes -> bases + cursors ----
__global__ __launch_bounds__(256) void scanB_k(const int* __restrict__ gcount,
                                               int* __restrict__ gbase,
                                               int* __restrict__ cursor) {
    __shared__ int sh[NBK];
    int t = threadIdx.x;
    int v = ((gcount[t] + 3) & ~3) + 3 * NPB;   // 4-aligned upper bound (per-node pad4)
    sh[t] = v;
    __syncthreads();
    for (int d = 1; d < NBK; d <<= 1) {
        int u = (t >= d) ? sh[t - d] : 0;
        __syncthreads();
        sh[t] += u;
        __syncthreads();
    }
    int ex = sh[t] - v;
    gbase[t] = ex;
    cursor[t] = ex;
}

// ---- A3: partition edges into bucket regions, packed (dst_local<<17)|src ----
__global__ __launch_bounds__(512) void partA_k(const int* __restrict__ src,
                                               const int* __restrict__ dst,
                                               int* __restrict__ cursor,
                                               int* __restrict__ bucketed, int ne) {
    constexpr int EPB = 8192;
    __shared__ int hist[NBK], lofs[NBK + 1], lcur[NBK], gbs[NBK], sc[NBK];
    __shared__ int stage[EPB];
    int t = threadIdx.x;
    int e0 = blockIdx.x * EPB;
    int e1 = min(e0 + EPB, ne);
    int cnt = e1 - e0;
    for (int i = t; i < NBK; i += 512) hist[i] = 0;
    __syncthreads();
    int sv[16], dv[16];
#pragma unroll
    for (int k = 0; k < 16; k++) {
        int e = e0 + t + k * 512;
        int s = 0, d = 0;
        if (e < e1) {
            s = src[e];
            d = dst[e];
            atomicAdd(&hist[d >> BSHIFT], 1);
        }
        sv[k] = s;
        dv[k] = d;
    }
    __syncthreads();
    if (t < NBK) sc[t] = hist[t];
    __syncthreads();
    for (int d = 1; d < NBK; d <<= 1) {
        int u = 0;
        if (t < NBK && t >= d) u = sc[t - d];
        __syncthreads();
        if (t < NBK) sc[t] += u;
        __syncthreads();
    }
    if (t < NBK) {
        int ex = sc[t] - hist[t];
        lofs[t] = ex;
        lcur[t] = ex;
        gbs[t] = hist[t] ? atomicAdd(&cursor[t], hist[t]) : 0;
    }
    if (t == 0) lofs[NBK] = cnt;
    __syncthreads();
#pragma unroll
    for (int k = 0; k < 16; k++) {
        int e = e0 + t + k * 512;
        if (e < e1) {
            int b = dv[k] >> BSHIFT;
            int q = atomicAdd(&lcur[b], 1);
            stage[q] = ((dv[k] & (NPB - 1)) << 17) | sv[k];
        }
    }
    __syncthreads();
    for (int idx = t; idx < cnt; idx += 512) {
        int lo = 0, hi = NBK;
        while (hi - lo > 1) {
            int mid = (lo + hi) >> 1;
            if (lofs[mid] <= idx) lo = mid; else hi = mid;
        }
        bucketed[gbs[lo] + (idx - lofs[lo])] = stage[idx];
    }
}

// ---- B: per-bucket CSR finalize with per-node pad4 (dummy src = nn -> zero row) ----
__global__ __launch_bounds__(1024) void csrB_k(const int* __restrict__ bucketed,
                                               const int* __restrict__ gbase,
                                               const int* __restrict__ gcount,
                                               int* __restrict__ csr,
                                               int* __restrict__ rowbeg,
                                               int* __restrict__ rend,
                                               float* __restrict__ dinv, int nn) {
    constexpr int CAP = 12288;
    __shared__ int cnt[NPB], ofs[NPB], cur[NPB];
    __shared__ int stage[CAP];
    __shared__ int ptot_s;
    int t = threadIdx.x;
    int b = blockIdx.x;
    int beg = gbase[b];
    int m = gcount[b];
    if (t < NPB) cnt[t] = 0;
    __syncthreads();
    for (int i = t; i < m; i += 1024)
        atomicAdd(&cnt[bucketed[beg + i] >> 17], 1);
    __syncthreads();
    int v = 0, pv = 0;
    if (t < NPB) { v = cnt[t]; pv = (v + 3) & ~3; ofs[t] = pv; }
    __syncthreads();
    for (int d = 1; d < NPB; d <<= 1) {
        int u = 0;
        if (t < NPB && t >= d) u = ofs[t - d];
        __syncthreads();
        if (t < NPB) ofs[t] += u;
        __syncthreads();
    }
    if (t == NPB - 1) ptot_s = ofs[t];
    int ex = 0;
    if (t < NPB) {
        ex = ofs[t] - pv;
        cur[t] = ex;
        int node = b * NPB + t;
        if (node < nn) {
            rowbeg[node] = beg + ex;
            rend[node]   = beg + ex + pv;
            dinv[node] = rsqrtf((float)(v + 1));   // +1 self-loop
        }
    }
    __syncthreads();
    int ptot = ptot_s;
    if (ptot <= CAP) {
        for (int i = t; i < m; i += 1024) {
            int e = bucketed[beg + i];
            int p = atomicAdd(&cur[e >> 17], 1);
            stage[p] = e & 0x1FFFF;
        }
        __syncthreads();
        if (t < NPB)
            for (int k = v; k < pv; k++) stage[ex + k] = nn;   // dummy pads
        __syncthreads();
        for (int i = t; i < ptot; i += 1024) csr[beg + i] = stage[i];
    } else {  // defensive fallback
        for (int i = t; i < m; i += 1024) {
            int e = bucketed[beg + i];
            int p = atomicAdd(&cur[e >> 17], 1);
            csr[beg + p] = e & 0x1FFFF;
        }
        __syncthreads();
        if (t < NPB)
            for (int k = v; k < pv; k++) csr[beg + ex + k] = nn;
    }
}

// ---- W prep: transpose + fp16 cast. WT1[j][k] (128x128), WT2[j][k] (64x128) ----
__global__ void prepW_k(const float* __restrict__ W1, const float* __restrict__ W2,
                        _Float16* __restrict__ WT1, _Float16* __restrict__ WT2) {
    int i = blockIdx.x * blockDim.x + threadIdx.x;
    if (i < 128 * 128) {
        int k = i >> 7, j = i & 127;
        WT1[j * 128 + k] = (_Float16)W1[i];
    }
    int i2 = i - 128 * 128;
    if (i2 >= 0 && i2 < 128 * 64) {
        int k = i2 >> 6, j = i2 & 63;
        WT2[j * 128 + k] = (_Float16)W2[i2];
    }
}

// ---------------- MFMA dense transform: H = X @ W, row-major fp16 out ----------------
// One wave per 16-row tile. Also zeroes dummy row nn (block 0) for the agg's pad entries.
// SCALE multiplies rows by dinv (h' = dinv .* XW).
template <int NO, bool SCALE, typename XT>
__global__ __launch_bounds__(256) void gemm_mfma_k(const XT* __restrict__ X,
                                                   const _Float16* __restrict__ WT,
                                                   const float* __restrict__ dinv,
                                                   _Float16* __restrict__ H, int nrows) {
    constexpr int K = 128;
    constexpr int NCT = NO / 16;
    if (blockIdx.x == 0 && threadIdx.x < NO)
        H[(size_t)nrows * NO + threadIdx.x] = (_Float16)0.f;   // dummy row nn = 0
    int wv = (int)((blockIdx.x * (size_t)blockDim.x + threadIdx.x) >> 6);
    int r0 = wv * 16;
    if (r0 >= nrows) return;
    int lane = threadIdx.x & 63;
    int lr = lane & 15;          // A-row / D-col
    int kg = lane >> 4;          // k-group
    int rg = r0 + lr;
    if (rg >= nrows) rg = nrows - 1;   // clamp (stores are guarded)

    half8 a[4];
    if constexpr (std::is_same<XT, float>::value) {
#pragma unroll
        for (int ks = 0; ks < 4; ks++) {
            const float* px = X + (size_t)rg * K + ks * 32 + kg * 8;
            float4 x0 = *(const float4*)px;
            float4 x1 = *(const float4*)(px + 4);
            half8 vv;
            vv[0] = (_Float16)x0.x; vv[1] = (_Float16)x0.y;
            vv[2] = (_Float16)x0.z; vv[3] = (_Float16)x0.w;
            vv[4] = (_Float16)x1.x; vv[5] = (_Float16)x1.y;
            vv[6] = (_Float16)x1.z; vv[7] = (_Float16)x1.w;
            a[ks] = vv;
        }
    } else {
#pragma unroll
        for (int ks = 0; ks < 4; ks++)
            a[ks] = *(const half8*)(X + (size_t)rg * K + ks * 32 + kg * 8);
    }

    f32x4 acc[NCT];
#pragma unroll
    for (int ct = 0; ct < NCT; ct++) acc[ct] = (f32x4){0.f, 0.f, 0.f, 0.f};
#pragma unroll
    for (int ct = 0; ct < NCT; ct++) {
#pragma unroll
        for (int ks = 0; ks < 4; ks++) {
            half8 b = *(const half8*)(WT + (size_t)(ct * 16 + lr) * K + ks * 32 + kg * 8);
            acc[ct] = __builtin_amdgcn_mfma_f32_16x16x32_f16(a[ks], b, acc[ct], 0, 0, 0);
        }
    }
    // epilogue: lane's 4 values per ct are rows kg*4+i, col lr (row-major store)
#pragma unroll
    for (int i = 0; i < 4; i++) {
        int rr = r0 + kg * 4 + i;
        if (rr < nrows) {
            float s = SCALE ? dinv[rr] : 1.f;
            _Float16* hp = H + (size_t)rr * NO + lr;
#pragma unroll
            for (int ct = 0; ct < NCT; ct++)
                hp[ct * 16] = (_Float16)(acc[ct][i] * s);
        }
    }
}

// ---------------- aggregation (round-5 structure + pad4 CSR, mask-free) ----------------
// out[n] = dinv[n]*(sum h'[s] + h'[n]) + b ; h' rows pre-scaled by dinv.
// One wave per node; 4 groups x 16 lanes; lane t owns a contiguous 1/16 of the row.
// Main loop: 16 edges/iter (4 per group, group-uniform csr reads, 1 fp16 pair-add level).
// pad4 segments (dummy src = nn -> zero row) make the 4-edge remainder loop mask-free.
template <int NF, bool RELU, bool OUTSCALE, typename OutT>
__global__ __launch_bounds__(256) void agg_k(const __half* __restrict__ H,
                                             const int* __restrict__ rowbeg,
                                             const int* __restrict__ rend,
                                             const int* __restrict__ csr,
                                             const float* __restrict__ dinv,
                                             const float* __restrict__ bias,
                                             OutT* __restrict__ Out, int nn) {
    constexpr int VPL = NF / 16;        // values per lane (8 or 4)
    constexpr int NV2 = VPL / 2;        // half2 per lane (4 or 2)
    int wid = (int)((blockIdx.x * (size_t)blockDim.x + threadIdx.x) >> 6);
    if (wid >= nn) return;
    int lane = threadIdx.x & 63;
    int g = lane >> 4, t = lane & 15;
    float acc[VPL];
#pragma unroll
    for (int j = 0; j < VPL; j++) acc[j] = 0.f;

    int beg = rowbeg[wid], end = rend[wid];
    int e0 = beg;
    // main: 16 edges per iteration (4 per group), all valid (pad4 dummies -> zero row)
    for (; e0 + 16 <= end; e0 += 16) {
        int eb = e0 + g * 4;
        int s0 = csr[eb + 0], s1 = csr[eb + 1], s2 = csr[eb + 2], s3 = csr[eb + 3];
        HVec<NV2> va = *((const HVec<NV2>*)(H + (size_t)s0 * NF) + t);
        HVec<NV2> vb = *((const HVec<NV2>*)(H + (size_t)s1 * NF) + t);
        HVec<NV2> vc = *((const HVec<NV2>*)(H + (size_t)s2 * NF) + t);
        HVec<NV2> vd = *((const HVec<NV2>*)(H + (size_t)s3 * NF) + t);
#pragma unroll
        for (int q = 0; q < NV2; q++) {
            __half2 pab = __hadd2(va.v[q], vb.v[q]);
            __half2 pcd = __hadd2(vc.v[q], vd.v[q]);
            float2 fab = __half22float2(pab);
            float2 fcd = __half22float2(pcd);
            acc[2 * q + 0] += fab.x + fcd.x;
            acc[2 * q + 1] += fab.y + fcd.y;
        }
    }
    // remainder: multiples of 4, one edge per group, mask-free
    for (; e0 < end; e0 += 4) {
        int s = csr[e0 + g];
        HVec<NV2> va = *((const HVec<NV2>*)(H + (size_t)s * NF) + t);
#pragma unroll
        for (int q = 0; q < NV2; q++) {
            float2 f = __half22float2(va.v[q]);
            acc[2 * q + 0] += f.x;
            acc[2 * q + 1] += f.y;
        }
    }
#pragma unroll
    for (int j = 0; j < VPL; j++) {
        acc[j] += __shfl_xor(acc[j], 16);
        acc[j] += __shfl_xor(acc[j], 32);
    }
    // self-loop (h'[wid], already dinv-scaled)
    HVec<NV2> hn = *((const HVec<NV2>*)(H + (size_t)wid * NF) + t);
#pragma unroll
    for (int q = 0; q < NV2; q++) {
        float2 f = __half22float2(hn.v[q]);
        acc[2 * q + 0] += f.x;
        acc[2 * q + 1] += f.y;
    }
    if (g == 0) {
        float dn = dinv[wid];
        float r[VPL];
#pragma unroll
        for (int j = 0; j < VPL; j++) {
            r[j] = acc[j] * dn + bias[t * VPL + j];
            if (RELU) r[j] = fmaxf(r[j], 0.f);
            if (OUTSCALE) r[j] *= dn;      // pre-scale for next layer's aggregation
        }
        if constexpr (std::is_same<OutT, __half>::value) {
            HVec<NV2> o;
#pragma unroll
            for (int q = 0; q < NV2; q++)
                o.v[q] = __floats2half2_rn(r[2 * q], r[2 * q + 1]);
            *((HVec<NV2>*)(Out + (size_t)wid * NF) + t) = o;
        } else {
#pragma unroll
            for (int q = 0; q < VPL / 4; q++) {
                float4 o;
                o.x = r[4 * q + 0]; o.y = r[4 * q + 1];
                o.z = r[4 * q + 2]; o.w = r[4 * q + 3];
                *((float4*)(Out + (size_t)wid * NF) + t * (VPL / 4) + q) = o;
            }
        }
    }
}

// ---------------- launch ----------------

extern "C" void kernel_launch(void* const* d_in, const int* in_sizes, int n_in,
                              void* d_out, int out_size, void* d_ws, size_t ws_size,
                              hipStream_t stream) {
    const float* x  = (const float*)d_in[0];
    const int* ei   = (const int*)d_in[1];
    const float* W1 = (const float*)d_in[2];
    const float* b1 = (const float*)d_in[3];
    const float* W2 = (const float*)d_in[4];
    const float* b2 = (const float*)d_in[5];
    float* out = (float*)d_out;

    const int IN = 128, HID = 128;
    int nn = in_sizes[0] / IN;     // 100000
    int ne = in_sizes[1] / 2;      // 1600000
    const int* src = ei;
    const int* dst = ei + ne;
    int nbuckets = (nn + NPB - 1) / NPB;   // 196 (<= NBK)

    char* w = (char*)d_ws;
    size_t off = 0;
    auto take = [&](size_t bytes) -> void* {
        void* p = w + off;
        off = (off + bytes + 255) & ~(size_t)255;
        return p;
    };
    int*      gcount = (int*)take(NBK * 4);
    int*      gbase  = (int*)take(NBK * 4);
    int*      cursor = (int*)take(NBK * 4);
    int*      rowbeg = (int*)take((size_t)nn * 4);
    int*      rend   = (int*)take((size_t)nn * 4);
    float*    dinv   = (float*)take((size_t)nn * 4);
    int*      csr    = (int*)take(((size_t)ne + (size_t)NBK * 1600) * 4);   // pad4 CSR
    _Float16* WT1    = (_Float16*)take(128 * 128 * 2);
    _Float16* WT2    = (_Float16*)take(64 * 128 * 2);
    _Float16* h      = (_Float16*)take((size_t)(nn + 1) * HID * 2);  // row-major + dummy row
    __half*   h1     = (__half*)take((size_t)nn * HID * 2);          // row-major
    _Float16* h2     = h;                  // reuse: h dead after agg1 ((nn+1)*64 fits)
    int*      bucketed = (int*)h;          // reuse: dead before gemm1 writes h

    (void)ws_size; (void)n_in; (void)out_size;

    hipMemsetAsync(gcount, 0, NBK * 4, stream);

    int tb = 256;
    histA_k<<<(ne + 4095) / 4096, 256, 0, stream>>>(dst, ne, gcount);
    scanB_k<<<1, NBK, 0, stream>>>(gcount, gbase, cursor);
    partA_k<<<(ne + 8191) / 8192, 512, 0, stream>>>(src, dst, cursor, bucketed, ne);
    csrB_k<<<nbuckets, 1024, 0, stream>>>(bucketed, gbase, gcount, csr, rowbeg, rend, dinv, nn);
    prepW_k<<<(128 * 128 + 128 * 64 + tb - 1) / tb, tb, 0, stream>>>(W1, W2, WT1, WT2);

    int gblocks = ((nn + 15) / 16 + 3) / 4;   // 1 wave per 16 rows, 4 waves/block

    // layer 1: h' = dinv .* (x @ W1)  [fp16 row-major] ; h1 = dinv .* relu(agg(h') + b1)
    gemm_mfma_k<128, true, float><<<gblocks, tb, 0, stream>>>(x, WT1, dinv, h, nn);
    agg_k<128, true, true, __half><<<(nn * 64 + tb - 1) / tb, tb, 0, stream>>>(
        (const __half*)h, rowbeg, rend, csr, dinv, b1, h1, nn);

    // layer 2: h2' = h1 @ W2 (already dinv-scaled) ; out = agg(h2') + b2  [fp32]
    gemm_mfma_k<64, false, __half><<<gblocks, tb, 0, stream>>>(h1, WT2, dinv, h2, nn);
    agg_k<64, false, false, float><<<(nn * 64 + tb - 1) / tb, tb, 0, stream>>>(
        (const __half*)h2, rowbeg, rend, csr, dinv, b2, out, nn);
}

// Round 12
// 205.935 us; speedup vs baseline: 1.5586x; 1.0522x over previous
//
#include <hip/hip_runtime.h>
#include <hip/hip_fp16.h>
#include <type_traits>

// Buckets of 512 nodes; fixed-capacity regions (mean count 8163, sigma ~90).
#define NBK 256
#define BSHIFT 9
#define NPB 512
#define BCAP 10240     // per-bucket 'bucketed' capacity (>23 sigma headroom)
#define CCAP 12288     // per-bucket csr capacity (BCAP + 3*NPB pad, rounded)
#define EPB 4096       // edges per partA block

template <int N> struct alignas(4 * N) HVec { __half2 v[N]; };

typedef _Float16 half8 __attribute__((ext_vector_type(8)));
typedef float f32x4 __attribute__((ext_vector_type(4)));

// ---- partA: single-pass partition into fixed-capacity bucket regions ----
// Per block: LDS hist over its EPB edges -> one global atomicAdd per bucket for the
// block's base -> LDS rank -> direct write. No global scan, no stage, no bsearch.
__global__ __launch_bounds__(512) void partA_k(const int* __restrict__ src,
                                               const int* __restrict__ dst,
                                               int* __restrict__ cursor,
                                               int* __restrict__ bucketed, int ne) {
    __shared__ int hist[NBK], gbs[NBK], lcur[NBK];
    int t = threadIdx.x;
    int e0 = blockIdx.x * EPB;
    int e1 = min(e0 + EPB, ne);
    for (int i = t; i < NBK; i += 512) { hist[i] = 0; lcur[i] = 0; }
    __syncthreads();
    int sv[EPB / 512], dv[EPB / 512];
#pragma unroll
    for (int k = 0; k < EPB / 512; k++) {
        int e = e0 + t + k * 512;
        int s = 0, d = -1;
        if (e < e1) {
            s = src[e];
            d = dst[e];
            atomicAdd(&hist[d >> BSHIFT], 1);
        }
        sv[k] = s;
        dv[k] = d;
    }
    __syncthreads();
    for (int i = t; i < NBK; i += 512)
        gbs[i] = hist[i] ? atomicAdd(&cursor[i], hist[i]) : 0;
    __syncthreads();
#pragma unroll
    for (int k = 0; k < EPB / 512; k++) {
        if (dv[k] >= 0) {
            int b = dv[k] >> BSHIFT;
            int q = gbs[b] + atomicAdd(&lcur[b], 1);
            if (q < BCAP)   // defensive (never expected)
                bucketed[(size_t)b * BCAP + q] = ((dv[k] & (NPB - 1)) << 17) | sv[k];
        }
    }
}

// ---- csrB: per-bucket CSR finalize, pad4 (dummy src = nn -> zero row), direct writes ----
__global__ __launch_bounds__(1024) void csrB_k(const int* __restrict__ bucketed,
                                               const int* __restrict__ cursor,
                                               int* __restrict__ csr,
                                               int* __restrict__ rowbeg,
                                               int* __restrict__ rend,
                                               float* __restrict__ dinv, int nn) {
    __shared__ int cnt[NPB], ofs[NPB], cur[NPB];
    int t = threadIdx.x;
    int b = blockIdx.x;
    int m = min(cursor[b], BCAP);
    const int* bk = bucketed + (size_t)b * BCAP;
    int cbase = b * CCAP;
    if (t < NPB) cnt[t] = 0;
    __syncthreads();
    for (int i = t; i < m; i += 1024)
        atomicAdd(&cnt[bk[i] >> 17], 1);
    __syncthreads();
    int v = 0, pv = 0;
    if (t < NPB) { v = cnt[t]; pv = (v + 3) & ~3; ofs[t] = pv; }
    __syncthreads();
    for (int d = 1; d < NPB; d <<= 1) {
        int u = 0;
        if (t < NPB && t >= d) u = ofs[t - d];
        __syncthreads();
        if (t < NPB) ofs[t] += u;
        __syncthreads();
    }
    if (t < NPB) {
        int ex = ofs[t] - pv;
        cur[t] = ex;
        int node = b * NPB + t;
        if (node < nn) {
            rowbeg[node] = cbase + ex;
            rend[node]   = cbase + ex + pv;
            dinv[node] = rsqrtf((float)(v + 1));   // +1 self-loop
        }
    }
    __syncthreads();
    // rank-scatter (runs ~deg per node, contiguous, single block -> single XCD)
    for (int i = t; i < m; i += 1024) {
        int e = bk[i];
        int p = atomicAdd(&cur[e >> 17], 1);
        csr[cbase + p] = e & 0x1FFFF;
    }
    // pads: disjoint addresses from the scatter (ranks >= v) -> no barrier needed
    if (t < NPB) {
        int ex = ofs[t] - pv;
        for (int k = v; k < pv; k++) csr[cbase + ex + k] = nn;
    }
}

// ---- W prep: transpose + fp16 cast. WT1[j][k] (128x128), WT2[j][k] (64x128) ----
__global__ void prepW_k(const float* __restrict__ W1, const float* __restrict__ W2,
                        _Float16* __restrict__ WT1, _Float16* __restrict__ WT2) {
    int i = blockIdx.x * blockDim.x + threadIdx.x;
    if (i < 128 * 128) {
        int k = i >> 7, j = i & 127;
        WT1[j * 128 + k] = (_Float16)W1[i];
    }
    int i2 = i - 128 * 128;
    if (i2 >= 0 && i2 < 128 * 64) {
        int k = i2 >> 6, j = i2 & 63;
        WT2[j * 128 + k] = (_Float16)W2[i2];
    }
}

// ---------------- MFMA dense transform: H = X @ W, row-major fp16 out ----------------
// One wave per 16-row tile. Block 0 also zeroes dummy row nn (agg pad target).
// SCALE multiplies rows by dinv (h' = dinv .* XW).
template <int NO, bool SCALE, typename XT>
__global__ __launch_bounds__(256) void gemm_mfma_k(const XT* __restrict__ X,
                                                   const _Float16* __restrict__ WT,
                                                   const float* __restrict__ dinv,
                                                   _Float16* __restrict__ H, int nrows) {
    constexpr int K = 128;
    constexpr int NCT = NO / 16;
    if (blockIdx.x == 0 && threadIdx.x < NO)
        H[(size_t)nrows * NO + threadIdx.x] = (_Float16)0.f;   // dummy row nn = 0
    int wv = (int)((blockIdx.x * (size_t)blockDim.x + threadIdx.x) >> 6);
    int r0 = wv * 16;
    if (r0 >= nrows) return;
    int lane = threadIdx.x & 63;
    int lr = lane & 15;          // A-row / D-col
    int kg = lane >> 4;          // k-group
    int rg = r0 + lr;
    if (rg >= nrows) rg = nrows - 1;   // clamp (stores are guarded)

    half8 a[4];
    if constexpr (std::is_same<XT, float>::value) {
#pragma unroll
        for (int ks = 0; ks < 4; ks++) {
            const float* px = X + (size_t)rg * K + ks * 32 + kg * 8;
            float4 x0 = *(const float4*)px;
            float4 x1 = *(const float4*)(px + 4);
            half8 vv;
            vv[0] = (_Float16)x0.x; vv[1] = (_Float16)x0.y;
            vv[2] = (_Float16)x0.z; vv[3] = (_Float16)x0.w;
            vv[4] = (_Float16)x1.x; vv[5] = (_Float16)x1.y;
            vv[6] = (_Float16)x1.z; vv[7] = (_Float16)x1.w;
            a[ks] = vv;
        }
    } else {
#pragma unroll
        for (int ks = 0; ks < 4; ks++)
            a[ks] = *(const half8*)(X + (size_t)rg * K + ks * 32 + kg * 8);
    }

    f32x4 acc[NCT];
#pragma unroll
    for (int ct = 0; ct < NCT; ct++) acc[ct] = (f32x4){0.f, 0.f, 0.f, 0.f};
#pragma unroll
    for (int ct = 0; ct < NCT; ct++) {
#pragma unroll
        for (int ks = 0; ks < 4; ks++) {
            half8 b = *(const half8*)(WT + (size_t)(ct * 16 + lr) * K + ks * 32 + kg * 8);
            acc[ct] = __builtin_amdgcn_mfma_f32_16x16x32_f16(a[ks], b, acc[ct], 0, 0, 0);
        }
    }
    // epilogue: lane's 4 values per ct are rows kg*4+i, col lr (row-major store)
#pragma unroll
    for (int i = 0; i < 4; i++) {
        int rr = r0 + kg * 4 + i;
        if (rr < nrows) {
            float s = SCALE ? dinv[rr] : 1.f;
            _Float16* hp = H + (size_t)rr * NO + lr;
#pragma unroll
            for (int ct = 0; ct < NCT; ct++)
                hp[ct * 16] = (_Float16)(acc[ct][i] * s);
        }
    }
}

// ---------------- aggregation (round-5 structure + pad4 CSR, mask-free) ----------------
// out[n] = dinv[n]*(sum h'[s] + h'[n]) + b ; h' rows pre-scaled by dinv.
// One wave per node; 4 groups x 16 lanes; lane t owns a contiguous 1/16 of the row.
// Main loop: 16 edges/iter (4 per group, group-uniform csr reads, 1 fp16 pair-add level).
// pad4 segments (dummy src = nn -> zero row) make the 4-edge remainder loop mask-free.
template <int NF, bool RELU, bool OUTSCALE, typename OutT>
__global__ __launch_bounds__(256) void agg_k(const __half* __restrict__ H,
                                             const int* __restrict__ rowbeg,
                                             const int* __restrict__ rend,
                                             const int* __restrict__ csr,
                                             const float* __restrict__ dinv,
                                             const float* __restrict__ bias,
                                             OutT* __restrict__ Out, int nn) {
    constexpr int VPL = NF / 16;        // values per lane (8 or 4)
    constexpr int NV2 = VPL / 2;        // half2 per lane (4 or 2)
    int wid = (int)((blockIdx.x * (size_t)blockDim.x + threadIdx.x) >> 6);
    if (wid >= nn) return;
    int lane = threadIdx.x & 63;
    int g = lane >> 4, t = lane & 15;
    float acc[VPL];
#pragma unroll
    for (int j = 0; j < VPL; j++) acc[j] = 0.f;

    int beg = rowbeg[wid], end = rend[wid];
    int e0 = beg;
    // main: 16 edges per iteration (4 per group), all valid (pad4 dummies -> zero row)
    for (; e0 + 16 <= end; e0 += 16) {
        int eb = e0 + g * 4;
        int s0 = csr[eb + 0], s1 = csr[eb + 1], s2 = csr[eb + 2], s3 = csr[eb + 3];
        HVec<NV2> va = *((const HVec<NV2>*)(H + (size_t)s0 * NF) + t);
        HVec<NV2> vb = *((const HVec<NV2>*)(H + (size_t)s1 * NF) + t);
        HVec<NV2> vc = *((const HVec<NV2>*)(H + (size_t)s2 * NF) + t);
        HVec<NV2> vd = *((const HVec<NV2>*)(H + (size_t)s3 * NF) + t);
#pragma unroll
        for (int q = 0; q < NV2; q++) {
            __half2 pab = __hadd2(va.v[q], vb.v[q]);
            __half2 pcd = __hadd2(vc.v[q], vd.v[q]);
            float2 fab = __half22float2(pab);
            float2 fcd = __half22float2(pcd);
            acc[2 * q + 0] += fab.x + fcd.x;
            acc[2 * q + 1] += fab.y + fcd.y;
        }
    }
    // remainder: multiples of 4, one edge per group, mask-free
    for (; e0 < end; e0 += 4) {
        int s = csr[e0 + g];
        HVec<NV2> va = *((const HVec<NV2>*)(H + (size_t)s * NF) + t);
#pragma unroll
        for (int q = 0; q < NV2; q++) {
            float2 f = __half22float2(va.v[q]);
            acc[2 * q + 0] += f.x;
            acc[2 * q + 1] += f.y;
        }
    }
#pragma unroll
    for (int j = 0; j < VPL; j++) {
        acc[j] += __shfl_xor(acc[j], 16);
        acc[j] += __shfl_xor(acc[j], 32);
    }
    // self-loop (h'[wid], already dinv-scaled)
    HVec<NV2> hn = *((const HVec<NV2>*)(H + (size_t)wid * NF) + t);
#pragma unroll
    for (int q = 0; q < NV2; q++) {
        float2 f = __half22float2(hn.v[q]);
        acc[2 * q + 0] += f.x;
        acc[2 * q + 1] += f.y;
    }
    if (g == 0) {
        float dn = dinv[wid];
        float r[VPL];
#pragma unroll
        for (int j = 0; j < VPL; j++) {
            r[j] = acc[j] * dn + bias[t * VPL + j];
            if (RELU) r[j] = fmaxf(r[j], 0.f);
            if (OUTSCALE) r[j] *= dn;      // pre-scale for next layer's aggregation
        }
        if constexpr (std::is_same<OutT, __half>::value) {
            HVec<NV2> o;
#pragma unroll
            for (int q = 0; q < NV2; q++)
                o.v[q] = __floats2half2_rn(r[2 * q], r[2 * q + 1]);
            *((HVec<NV2>*)(Out + (size_t)wid * NF) + t) = o;
        } else {
#pragma unroll
            for (int q = 0; q < VPL / 4; q++) {
                float4 o;
                o.x = r[4 * q + 0]; o.y = r[4 * q + 1];
                o.z = r[4 * q + 2]; o.w = r[4 * q + 3];
                *((float4*)(Out + (size_t)wid * NF) + t * (VPL / 4) + q) = o;
            }
        }
    }
}

// ---------------- launch ----------------

extern "C" void kernel_launch(void* const* d_in, const int* in_sizes, int n_in,
                              void* d_out, int out_size, void* d_ws, size_t ws_size,
                              hipStream_t stream) {
    const float* x  = (const float*)d_in[0];
    const int* ei   = (const int*)d_in[1];
    const float* W1 = (const float*)d_in[2];
    const float* b1 = (const float*)d_in[3];
    const float* W2 = (const float*)d_in[4];
    const float* b2 = (const float*)d_in[5];
    float* out = (float*)d_out;

    const int IN = 128, HID = 128;
    int nn = in_sizes[0] / IN;     // 100000
    int ne = in_sizes[1] / 2;      // 1600000
    const int* src = ei;
    const int* dst = ei + ne;
    int nbuckets = (nn + NPB - 1) / NPB;   // 196 (<= NBK)

    char* w = (char*)d_ws;
    size_t off = 0;
    auto take = [&](size_t bytes) -> void* {
        void* p = w + off;
        off = (off + bytes + 255) & ~(size_t)255;
        return p;
    };
    int*      cursor = (int*)take(NBK * 4);
    int*      rowbeg = (int*)take((size_t)nn * 4);
    int*      rend   = (int*)take((size_t)nn * 4);
    float*    dinv   = (float*)take((size_t)nn * 4);
    int*      csr    = (int*)take((size_t)NBK * CCAP * 4);            // fixed-cap regions
    _Float16* WT1    = (_Float16*)take(128 * 128 * 2);
    _Float16* WT2    = (_Float16*)take(64 * 128 * 2);
    _Float16* h      = (_Float16*)take((size_t)(nn + 1) * HID * 2);   // row-major + dummy row
    __half*   h1     = (__half*)take((size_t)nn * HID * 2);           // row-major
    _Float16* h2     = h;                  // reuse: h dead after agg1 ((nn+1)*64 fits)
    int*      bucketed = (int*)h;          // reuse: NBK*BCAP*4 = 10.5MB <= 25.6MB, dead pre-gemm1

    (void)ws_size; (void)n_in; (void)out_size;

    hipMemsetAsync(cursor, 0, NBK * 4, stream);

    int tb = 256;
    partA_k<<<(ne + EPB - 1) / EPB, 512, 0, stream>>>(src, dst, cursor, bucketed, ne);
    csrB_k<<<nbuckets, 1024, 0, stream>>>(bucketed, cursor, csr, rowbeg, rend, dinv, nn);
    prepW_k<<<(128 * 128 + 128 * 64 + tb - 1) / tb, tb, 0, stream>>>(W1, W2, WT1, WT2);

    int gblocks = ((nn + 15) / 16 + 3) / 4;   // 1 wave per 16 rows, 4 waves/block

    // layer 1: h' = dinv .* (x @ W1)  [fp16 row-major] ; h1 = dinv .* relu(agg(h') + b1)
    gemm_mfma_k<128, true, float><<<gblocks, tb, 0, stream>>>(x, WT1, dinv, h, nn);
    agg_k<128, true, true, __half><<<(nn * 64 + tb - 1) / tb, tb, 0, stream>>>(
        (const __half*)h, rowbeg, rend, csr, dinv, b1, h1, nn);

    // layer 2: h2' = h1 @ W2 (already dinv-scaled) ; out = agg(h2') + b2  [fp32]
    gemm_mfma_k<64, false, __half><<<gblocks, tb, 0, stream>>>(h1, WT2, dinv, h2, nn);
    agg_k<64, false, false, float><<<(nn * 64 + tb - 1) / tb, tb, 0, stream>>>(
        (const __half*)h2, rowbeg, rend, csr, dinv, b2, out, nn);
}

// Round 13
// 202.098 us; speedup vs baseline: 1.5882x; 1.0190x over previous
//
#include <hip/hip_runtime.h>
#include <hip/hip_fp16.h>
#include <type_traits>

// Buckets of 512 nodes; fixed-capacity regions (mean count 8163, sigma ~90).
#define NBK 256
#define BSHIFT 9
#define NPB 512
#define BCAP 10240     // per-bucket 'bucketed' capacity
#define CCAP 12288     // per-bucket csr capacity (count + pad8 worst case fits)
#define EPB 4096       // edges per partA block

template <int N> struct alignas(4 * N) HVec { __half2 v[N]; };

typedef _Float16 half8 __attribute__((ext_vector_type(8)));
typedef float f32x4 __attribute__((ext_vector_type(4)));

// ---- prep0: zero bucket cursors + transpose W1/W2 to fp16 WT[j][k] ----
__global__ void prep0_k(const float* __restrict__ W1, const float* __restrict__ W2,
                        _Float16* __restrict__ WT1, _Float16* __restrict__ WT2,
                        int* __restrict__ cursor) {
    int i = blockIdx.x * blockDim.x + threadIdx.x;
    if (i < NBK) cursor[i] = 0;
    if (i < 128 * 128) {
        int k = i >> 7, j = i & 127;
        WT1[j * 128 + k] = (_Float16)W1[i];
    }
    int i2 = i - 128 * 128;
    if (i2 >= 0 && i2 < 128 * 64) {
        int k = i2 >> 6, j = i2 & 63;
        WT2[j * 128 + k] = (_Float16)W2[i2];
    }
}

// ---- partA: single-pass partition into fixed-capacity bucket regions ----
// ONE LDS atomic per edge: counting atomicAdd's return value is the rank.
__global__ __launch_bounds__(512) void partA_k(const int* __restrict__ src,
                                               const int* __restrict__ dst,
                                               int* __restrict__ cursor,
                                               int* __restrict__ bucketed, int ne) {
    __shared__ int hist[NBK], gbs[NBK];
    int t = threadIdx.x;
    int e0 = blockIdx.x * EPB;
    int e1 = min(e0 + EPB, ne);
    for (int i = t; i < NBK; i += 512) hist[i] = 0;
    __syncthreads();
    int sv[EPB / 512], dv[EPB / 512], rv[EPB / 512];
#pragma unroll
    for (int k = 0; k < EPB / 512; k++) {
        int e = e0 + t + k * 512;
        int s = 0, d = -1, r = 0;
        if (e < e1) {
            s = src[e];
            d = dst[e];
            r = atomicAdd(&hist[d >> BSHIFT], 1);   // rank within block's bucket run
        }
        sv[k] = s; dv[k] = d; rv[k] = r;
    }
    __syncthreads();
    for (int i = t; i < NBK; i += 512)
        gbs[i] = hist[i] ? atomicAdd(&cursor[i], hist[i]) : 0;
    __syncthreads();
#pragma unroll
    for (int k = 0; k < EPB / 512; k++) {
        if (dv[k] >= 0) {
            int b = dv[k] >> BSHIFT;
            int q = gbs[b] + rv[k];
            if (q < BCAP)   // defensive (never expected)
                bucketed[(size_t)b * BCAP + q] = ((dv[k] & (NPB - 1)) << 17) | sv[k];
        }
    }
}

// ---- csrB: per-bucket CSR finalize, pad8 (dummy src = nn -> zero row) ----
// ONE LDS atomic per edge (rank from counting pass), no stage buffer.
__global__ __launch_bounds__(1024) void csrB_k(const int* __restrict__ bucketed,
                                               const int* __restrict__ cursor,
                                               int* __restrict__ csr,
                                               int* __restrict__ rowbeg,
                                               int* __restrict__ rend,
                                               float* __restrict__ dinv, int nn) {
    __shared__ int cnt[NPB], ofs[NPB], exs[NPB];
    int t = threadIdx.x;
    int b = blockIdx.x;
    int m = min(cursor[b], BCAP);
    const int* bk = bucketed + (size_t)b * BCAP;
    int cbase = b * CCAP;
    if (t < NPB) cnt[t] = 0;
    __syncthreads();
    int rk[(BCAP + 1023) / 1024];
    int nit = 0;
    for (int i = t; i < m; i += 1024)
        rk[nit++] = atomicAdd(&cnt[bk[i] >> 17], 1);   // rank within node
    __syncthreads();
    int v = 0, pv = 0;
    if (t < NPB) { v = cnt[t]; pv = (v + 7) & ~7; ofs[t] = pv; }
    __syncthreads();
    for (int d = 1; d < NPB; d <<= 1) {
        int u = 0;
        if (t < NPB && t >= d) u = ofs[t - d];
        __syncthreads();
        if (t < NPB) ofs[t] += u;
        __syncthreads();
    }
    if (t < NPB) {
        int ex = ofs[t] - pv;
        exs[t] = ex;
        int node = b * NPB + t;
        if (node < nn) {
            rowbeg[node] = cbase + ex;
            rend[node]   = cbase + ex + pv;
            dinv[node] = rsqrtf((float)(v + 1));   // +1 self-loop
        }
    }
    __syncthreads();
    nit = 0;
    for (int i = t; i < m; i += 1024) {
        int e = bk[i];
        csr[cbase + exs[e >> 17] + rk[nit++]] = e & 0x1FFFF;
    }
    // pads (ranks v..pv-1): disjoint from scatter addresses, no barrier needed
    if (t < NPB) {
        int ex = exs[t];
        for (int k = v; k < pv; k++) csr[cbase + ex + k] = nn;
    }
}

// ---------------- MFMA dense transform: H = X @ W, row-major fp16 out ----------------
// One wave per 16-row tile. Block 0 also zeroes dummy row nn (agg pad target).
// SCALE multiplies rows by dinv (h' = dinv .* XW).
template <int NO, bool SCALE, typename XT>
__global__ __launch_bounds__(256) void gemm_mfma_k(const XT* __restrict__ X,
                                                   const _Float16* __restrict__ WT,
                                                   const float* __restrict__ dinv,
                                                   _Float16* __restrict__ H, int nrows) {
    constexpr int K = 128;
    constexpr int NCT = NO / 16;
    if (blockIdx.x == 0 && threadIdx.x < NO)
        H[(size_t)nrows * NO + threadIdx.x] = (_Float16)0.f;   // dummy row nn = 0
    int wv = (int)((blockIdx.x * (size_t)blockDim.x + threadIdx.x) >> 6);
    int r0 = wv * 16;
    if (r0 >= nrows) return;
    int lane = threadIdx.x & 63;
    int lr = lane & 15;          // A-row / D-col
    int kg = lane >> 4;          // k-group
    int rg = r0 + lr;
    if (rg >= nrows) rg = nrows - 1;   // clamp (stores are guarded)

    half8 a[4];
    if constexpr (std::is_same<XT, float>::value) {
#pragma unroll
        for (int ks = 0; ks < 4; ks++) {
            const float* px = X + (size_t)rg * K + ks * 32 + kg * 8;
            float4 x0 = *(const float4*)px;
            float4 x1 = *(const float4*)(px + 4);
            half8 vv;
            vv[0] = (_Float16)x0.x; vv[1] = (_Float16)x0.y;
            vv[2] = (_Float16)x0.z; vv[3] = (_Float16)x0.w;
            vv[4] = (_Float16)x1.x; vv[5] = (_Float16)x1.y;
            vv[6] = (_Float16)x1.z; vv[7] = (_Float16)x1.w;
            a[ks] = vv;
        }
    } else {
#pragma unroll
        for (int ks = 0; ks < 4; ks++)
            a[ks] = *(const half8*)(X + (size_t)rg * K + ks * 32 + kg * 8);
    }

    f32x4 acc[NCT];
#pragma unroll
    for (int ct = 0; ct < NCT; ct++) acc[ct] = (f32x4){0.f, 0.f, 0.f, 0.f};
#pragma unroll
    for (int ct = 0; ct < NCT; ct++) {
#pragma unroll
        for (int ks = 0; ks < 4; ks++) {
            half8 b = *(const half8*)(WT + (size_t)(ct * 16 + lr) * K + ks * 32 + kg * 8);
            acc[ct] = __builtin_amdgcn_mfma_f32_16x16x32_f16(a[ks], b, acc[ct], 0, 0, 0);
        }
    }
#pragma unroll
    for (int i = 0; i < 4; i++) {
        int rr = r0 + kg * 4 + i;
        if (rr < nrows) {
            float s = SCALE ? dinv[rr] : 1.f;
            _Float16* hp = H + (size_t)rr * NO + lr;
#pragma unroll
            for (int ct = 0; ct < NCT; ct++)
                hp[ct * 16] = (_Float16)(acc[ct][i] * s);
        }
    }
}

// ---------------- agg layer 1 (NF=128): 16-lane groups, 4 rows/instr ----------------
// out[n] = dinv[n]*(sum h'[s] + h'[n]) + b ; h' rows pre-scaled by dinv. pad8 CSR,
// dummy src = nn -> zero row; main 16 edges/iter, remainder 4/iter, all mask-free.
template <bool RELU, bool OUTSCALE>
__global__ __launch_bounds__(256) void agg128_k(const __half* __restrict__ H,
                                                const int* __restrict__ rowbeg,
                                                const int* __restrict__ rend,
                                                const int* __restrict__ csr,
                                                const float* __restrict__ dinv,
                                                const float* __restrict__ bias,
                                                __half* __restrict__ Out, int nn) {
    constexpr int NF = 128;
    int wid = (int)((blockIdx.x * (size_t)blockDim.x + threadIdx.x) >> 6);
    if (wid >= nn) return;
    int lane = threadIdx.x & 63;
    int g = lane >> 4, t = lane & 15;
    float acc[8];
#pragma unroll
    for (int j = 0; j < 8; j++) acc[j] = 0.f;

    int beg = rowbeg[wid], end = rend[wid];
    int e0 = beg;
    for (; e0 + 16 <= end; e0 += 16) {
        int eb = e0 + g * 4;
        int s0 = csr[eb + 0], s1 = csr[eb + 1], s2 = csr[eb + 2], s3 = csr[eb + 3];
        HVec<4> va = *((const HVec<4>*)(H + (size_t)s0 * NF) + t);
        HVec<4> vb = *((const HVec<4>*)(H + (size_t)s1 * NF) + t);
        HVec<4> vc = *((const HVec<4>*)(H + (size_t)s2 * NF) + t);
        HVec<4> vd = *((const HVec<4>*)(H + (size_t)s3 * NF) + t);
#pragma unroll
        for (int q = 0; q < 4; q++) {
            __half2 pab = __hadd2(va.v[q], vb.v[q]);
            __half2 pcd = __hadd2(vc.v[q], vd.v[q]);
            float2 fab = __half22float2(pab);
            float2 fcd = __half22float2(pcd);
            acc[2 * q + 0] += fab.x + fcd.x;
            acc[2 * q + 1] += fab.y + fcd.y;
        }
    }
    for (; e0 < end; e0 += 4) {
        int s = csr[e0 + g];
        HVec<4> va = *((const HVec<4>*)(H + (size_t)s * NF) + t);
#pragma unroll
        for (int q = 0; q < 4; q++) {
            float2 f = __half22float2(va.v[q]);
            acc[2 * q + 0] += f.x;
            acc[2 * q + 1] += f.y;
        }
    }
#pragma unroll
    for (int j = 0; j < 8; j++) {
        acc[j] += __shfl_xor(acc[j], 16);
        acc[j] += __shfl_xor(acc[j], 32);
    }
    HVec<4> hn = *((const HVec<4>*)(H + (size_t)wid * NF) + t);
#pragma unroll
    for (int q = 0; q < 4; q++) {
        float2 f = __half22float2(hn.v[q]);
        acc[2 * q + 0] += f.x;
        acc[2 * q + 1] += f.y;
    }
    if (g == 0) {
        float dn = dinv[wid];
        float r[8];
#pragma unroll
        for (int j = 0; j < 8; j++) {
            r[j] = acc[j] * dn + bias[t * 8 + j];
            if (RELU) r[j] = fmaxf(r[j], 0.f);
            if (OUTSCALE) r[j] *= dn;
        }
        HVec<4> o;
#pragma unroll
        for (int q = 0; q < 4; q++)
            o.v[q] = __floats2half2_rn(r[2 * q], r[2 * q + 1]);
        *((HVec<4>*)(Out + (size_t)wid * NF) + t) = o;
    }
}

// ---------------- agg layer 2 (NF=64): 8-lane groups, 8 rows/instr ----------------
// Row = 128B = 8 lanes x 16B -> one gather instruction covers 8 rows (1KB, maximal).
// Main: 16 edges/iter with 2 gather instrs; remainder: 8/iter with 1. pad8 mask-free.
template <bool RELU>
__global__ __launch_bounds__(256) void agg64_k(const __half* __restrict__ H,
                                               const int* __restrict__ rowbeg,
                                               const int* __restrict__ rend,
                                               const int* __restrict__ csr,
                                               const float* __restrict__ dinv,
                                               const float* __restrict__ bias,
                                               float* __restrict__ Out, int nn) {
    constexpr int NF = 64;
    int wid = (int)((blockIdx.x * (size_t)blockDim.x + threadIdx.x) >> 6);
    if (wid >= nn) return;
    int lane = threadIdx.x & 63;
    int g = lane >> 3, t = lane & 7;
    float acc[8];
#pragma unroll
    for (int j = 0; j < 8; j++) acc[j] = 0.f;

    int beg = rowbeg[wid], end = rend[wid];
    int e0 = beg;
    for (; e0 + 16 <= end; e0 += 16) {
        int eb = e0 + g * 2;
        int s0 = csr[eb], s1 = csr[eb + 1];
        HVec<4> va = *((const HVec<4>*)(H + (size_t)s0 * NF) + t);
        HVec<4> vb = *((const HVec<4>*)(H + (size_t)s1 * NF) + t);
#pragma unroll
        for (int q = 0; q < 4; q++) {
            __half2 p = __hadd2(va.v[q], vb.v[q]);
            float2 f = __half22float2(p);
            acc[2 * q + 0] += f.x;
            acc[2 * q + 1] += f.y;
        }
    }
    for (; e0 < end; e0 += 8) {
        int s = csr[e0 + g];
        HVec<4> va = *((const HVec<4>*)(H + (size_t)s * NF) + t);
#pragma unroll
        for (int q = 0; q < 4; q++) {
            float2 f = __half22float2(va.v[q]);
            acc[2 * q + 0] += f.x;
            acc[2 * q + 1] += f.y;
        }
    }
#pragma unroll
    for (int j = 0; j < 8; j++) {
        acc[j] += __shfl_xor(acc[j], 8);
        acc[j] += __shfl_xor(acc[j], 16);
        acc[j] += __shfl_xor(acc[j], 32);
    }
    HVec<4> hn = *((const HVec<4>*)(H + (size_t)wid * NF) + t);
#pragma unroll
    for (int q = 0; q < 4; q++) {
        float2 f = __half22float2(hn.v[q]);
        acc[2 * q + 0] += f.x;
        acc[2 * q + 1] += f.y;
    }
    if (g == 0) {
        float dn = dinv[wid];
        float r[8];
#pragma unroll
        for (int j = 0; j < 8; j++) {
            r[j] = acc[j] * dn + bias[t * 8 + j];
            if (RELU) r[j] = fmaxf(r[j], 0.f);
        }
        float* op = Out + (size_t)wid * NF + t * 8;
        float4 o0, o1;
        o0.x = r[0]; o0.y = r[1]; o0.z = r[2]; o0.w = r[3];
        o1.x = r[4]; o1.y = r[5]; o1.z = r[6]; o1.w = r[7];
        *(float4*)op = o0;
        *(float4*)(op + 4) = o1;
    }
}

// ---------------- launch ----------------

extern "C" void kernel_launch(void* const* d_in, const int* in_sizes, int n_in,
                              void* d_out, int out_size, void* d_ws, size_t ws_size,
                              hipStream_t stream) {
    const float* x  = (const float*)d_in[0];
    const int* ei   = (const int*)d_in[1];
    const float* W1 = (const float*)d_in[2];
    const float* b1 = (const float*)d_in[3];
    const float* W2 = (const float*)d_in[4];
    const float* b2 = (const float*)d_in[5];
    float* out = (float*)d_out;

    const int IN = 128, HID = 128;
    int nn = in_sizes[0] / IN;     // 100000
    int ne = in_sizes[1] / 2;      // 1600000
    const int* src = ei;
    const int* dst = ei + ne;
    int nbuckets = (nn + NPB - 1) / NPB;   // 196 (<= NBK)

    char* w = (char*)d_ws;
    size_t off = 0;
    auto take = [&](size_t bytes) -> void* {
        void* p = w + off;
        off = (off + bytes + 255) & ~(size_t)255;
        return p;
    };
    int*      cursor = (int*)take(NBK * 4);
    int*      rowbeg = (int*)take((size_t)nn * 4);
    int*      rend   = (int*)take((size_t)nn * 4);
    float*    dinv   = (float*)take((size_t)nn * 4);
    int*      csr    = (int*)take((size_t)NBK * CCAP * 4);            // fixed-cap regions
    _Float16* WT1    = (_Float16*)take(128 * 128 * 2);
    _Float16* WT2    = (_Float16*)take(64 * 128 * 2);
    _Float16* h      = (_Float16*)take((size_t)(nn + 1) * HID * 2);   // row-major + dummy row
    __half*   h1     = (__half*)take((size_t)nn * HID * 2);           // row-major
    _Float16* h2     = h;                  // reuse: h dead after agg1 ((nn+1)*64 fits)
    int*      bucketed = (int*)h;          // reuse: NBK*BCAP*4 = 10.5MB <= 25.8MB, dead pre-gemm1

    (void)ws_size; (void)n_in; (void)out_size;

    int tb = 256;
    prep0_k<<<(128 * 128 + 128 * 64 + tb - 1) / tb, tb, 0, stream>>>(W1, W2, WT1, WT2, cursor);
    partA_k<<<(ne + EPB - 1) / EPB, 512, 0, stream>>>(src, dst, cursor, bucketed, ne);
    csrB_k<<<nbuckets, 1024, 0, stream>>>(bucketed, cursor, csr, rowbeg, rend, dinv, nn);

    int gblocks = ((nn + 15) / 16 + 3) / 4;   // 1 wave per 16 rows, 4 waves/block

    // layer 1: h' = dinv .* (x @ W1)  [fp16 row-major] ; h1 = dinv .* relu(agg(h') + b1)
    gemm_mfma_k<128, true, float><<<gblocks, tb, 0, stream>>>(x, WT1, dinv, h, nn);
    agg128_k<true, true><<<(nn * 64 + tb - 1) / tb, tb, 0, stream>>>(
        (const __half*)h, rowbeg, rend, csr, dinv, b1, (__half*)h1, nn);

    // layer 2: h2' = h1 @ W2 (already dinv-scaled) ; out = agg(h2') + b2  [fp32]
    gemm_mfma_k<64, false, __half><<<gblocks, tb, 0, stream>>>(h1, WT2, dinv, h2, nn);
    agg64_k<false><<<(nn * 64 + tb - 1) / tb, tb, 0, stream>>>(
        (const __half*)h2, rowbeg, rend, csr, dinv, b2, out, nn);
}

// Round 14
// 197.213 us; speedup vs baseline: 1.6275x; 1.0248x over previous
//
#include <hip/hip_runtime.h>
#include <hip/hip_fp16.h>
#include <type_traits>

// Buckets of 512 nodes; fixed-capacity regions (mean count 8163, sigma ~90).
#define NBK 256
#define BSHIFT 9
#define NPB 512
#define BCAP 10240     // per-bucket 'bucketed' capacity
#define CCAP 12288     // per-bucket csr capacity (count + pad8 worst case fits)
#define EPB 4096       // edges per partA block

template <int N> struct alignas(4 * N) HVec { __half2 v[N]; };

typedef _Float16 half8 __attribute__((ext_vector_type(8)));
typedef float f32x4 __attribute__((ext_vector_type(4)));

// ---- prep0: zero bucket cursors + transpose W1/W2 to fp16 WT[j][k] ----
__global__ void prep0_k(const float* __restrict__ W1, const float* __restrict__ W2,
                        _Float16* __restrict__ WT1, _Float16* __restrict__ WT2,
                        int* __restrict__ cursor) {
    int i = blockIdx.x * blockDim.x + threadIdx.x;
    if (i < NBK) cursor[i] = 0;
    if (i < 128 * 128) {
        int k = i >> 7, j = i & 127;
        WT1[j * 128 + k] = (_Float16)W1[i];
    }
    int i2 = i - 128 * 128;
    if (i2 >= 0 && i2 < 128 * 64) {
        int k = i2 >> 6, j = i2 & 63;
        WT2[j * 128 + k] = (_Float16)W2[i2];
    }
}

// ---- partA: single-pass partition into fixed-capacity bucket regions ----
__global__ __launch_bounds__(512) void partA_k(const int* __restrict__ src,
                                               const int* __restrict__ dst,
                                               int* __restrict__ cursor,
                                               int* __restrict__ bucketed, int ne) {
    __shared__ int hist[NBK], gbs[NBK];
    int t = threadIdx.x;
    int e0 = blockIdx.x * EPB;
    int e1 = min(e0 + EPB, ne);
    for (int i = t; i < NBK; i += 512) hist[i] = 0;
    __syncthreads();
    int sv[EPB / 512], dv[EPB / 512], rv[EPB / 512];
#pragma unroll
    for (int k = 0; k < EPB / 512; k++) {
        int e = e0 + t + k * 512;
        int s = 0, d = -1, r = 0;
        if (e < e1) {
            s = src[e];
            d = dst[e];
            r = atomicAdd(&hist[d >> BSHIFT], 1);   // rank within block's bucket run
        }
        sv[k] = s; dv[k] = d; rv[k] = r;
    }
    __syncthreads();
    for (int i = t; i < NBK; i += 512)
        gbs[i] = hist[i] ? atomicAdd(&cursor[i], hist[i]) : 0;
    __syncthreads();
#pragma unroll
    for (int k = 0; k < EPB / 512; k++) {
        if (dv[k] >= 0) {
            int b = dv[k] >> BSHIFT;
            int q = gbs[b] + rv[k];
            if (q < BCAP)   // defensive (never expected)
                bucketed[(size_t)b * BCAP + q] = ((dv[k] & (NPB - 1)) << 17) | sv[k];
        }
    }
}

// ---- csrB: per-bucket CSR finalize, pad8 (dummy src = nn -> zero row) ----
__global__ __launch_bounds__(1024) void csrB_k(const int* __restrict__ bucketed,
                                               const int* __restrict__ cursor,
                                               int* __restrict__ csr,
                                               int* __restrict__ rowbeg,
                                               int* __restrict__ rend,
                                               float* __restrict__ dinv, int nn) {
    __shared__ int cnt[NPB], ofs[NPB], exs[NPB];
    int t = threadIdx.x;
    int b = blockIdx.x;
    int m = min(cursor[b], BCAP);
    const int* bk = bucketed + (size_t)b * BCAP;
    int cbase = b * CCAP;
    if (t < NPB) cnt[t] = 0;
    __syncthreads();
    int rk[(BCAP + 1023) / 1024];
    int nit = 0;
    for (int i = t; i < m; i += 1024)
        rk[nit++] = atomicAdd(&cnt[bk[i] >> 17], 1);   // rank within node
    __syncthreads();
    int v = 0, pv = 0;
    if (t < NPB) { v = cnt[t]; pv = (v + 7) & ~7; ofs[t] = pv; }
    __syncthreads();
    for (int d = 1; d < NPB; d <<= 1) {
        int u = 0;
        if (t < NPB && t >= d) u = ofs[t - d];
        __syncthreads();
        if (t < NPB) ofs[t] += u;
        __syncthreads();
    }
    if (t < NPB) {
        int ex = ofs[t] - pv;
        exs[t] = ex;
        int node = b * NPB + t;
        if (node < nn) {
            rowbeg[node] = cbase + ex;
            rend[node]   = cbase + ex + pv;
            dinv[node] = rsqrtf((float)(v + 1));   // +1 self-loop
        }
    }
    __syncthreads();
    nit = 0;
    for (int i = t; i < m; i += 1024) {
        int e = bk[i];
        csr[cbase + exs[e >> 17] + rk[nit++]] = e & 0x1FFFF;
    }
    if (t < NPB) {
        int ex = exs[t];
        for (int k = v; k < pv; k++) csr[cbase + ex + k] = nn;   // pads, disjoint addrs
    }
}

// ---------------- MFMA dense transform (layer 1): h' = dinv .* (X @ W1), fp16 ----------------
template <int NO, bool SCALE, typename XT>
__global__ __launch_bounds__(256) void gemm_mfma_k(const XT* __restrict__ X,
                                                   const _Float16* __restrict__ WT,
                                                   const float* __restrict__ dinv,
                                                   _Float16* __restrict__ H, int nrows) {
    constexpr int K = 128;
    constexpr int NCT = NO / 16;
    if (blockIdx.x == 0 && threadIdx.x < NO)
        H[(size_t)nrows * NO + threadIdx.x] = (_Float16)0.f;   // dummy row nn = 0
    int wv = (int)((blockIdx.x * (size_t)blockDim.x + threadIdx.x) >> 6);
    int r0 = wv * 16;
    if (r0 >= nrows) return;
    int lane = threadIdx.x & 63;
    int lr = lane & 15;          // A-row / D-col
    int kg = lane >> 4;          // k-group
    int rg = r0 + lr;
    if (rg >= nrows) rg = nrows - 1;   // clamp (stores are guarded)

    half8 a[4];
    if constexpr (std::is_same<XT, float>::value) {
#pragma unroll
        for (int ks = 0; ks < 4; ks++) {
            const float* px = X + (size_t)rg * K + ks * 32 + kg * 8;
            float4 x0 = *(const float4*)px;
            float4 x1 = *(const float4*)(px + 4);
            half8 vv;
            vv[0] = (_Float16)x0.x; vv[1] = (_Float16)x0.y;
            vv[2] = (_Float16)x0.z; vv[3] = (_Float16)x0.w;
            vv[4] = (_Float16)x1.x; vv[5] = (_Float16)x1.y;
            vv[6] = (_Float16)x1.z; vv[7] = (_Float16)x1.w;
            a[ks] = vv;
        }
    } else {
#pragma unroll
        for (int ks = 0; ks < 4; ks++)
            a[ks] = *(const half8*)(X + (size_t)rg * K + ks * 32 + kg * 8);
    }

    f32x4 acc[NCT];
#pragma unroll
    for (int ct = 0; ct < NCT; ct++) acc[ct] = (f32x4){0.f, 0.f, 0.f, 0.f};
#pragma unroll
    for (int ct = 0; ct < NCT; ct++) {
#pragma unroll
        for (int ks = 0; ks < 4; ks++) {
            half8 b = *(const half8*)(WT + (size_t)(ct * 16 + lr) * K + ks * 32 + kg * 8);
            acc[ct] = __builtin_amdgcn_mfma_f32_16x16x32_f16(a[ks], b, acc[ct], 0, 0, 0);
        }
    }
#pragma unroll
    for (int i = 0; i < 4; i++) {
        int rr = r0 + kg * 4 + i;
        if (rr < nrows) {
            float s = SCALE ? dinv[rr] : 1.f;
            _Float16* hp = H + (size_t)rr * NO + lr;
#pragma unroll
            for (int ct = 0; ct < NCT; ct++)
                hp[ct * 16] = (_Float16)(acc[ct][i] * s);
        }
    }
}

// ---------------- FUSED agg1 + gemm2 ----------------
// Block = 1024 threads = 16 waves = 16 nodes. Each wave runs the agg128 body for its
// node (h1 row = dinv*relu(agg+b1)*dinv, fp16) and parks it in LDS (272B stride ->
// 2-way bank alias, free). Barrier. Waves 0..3 each compute one 16-col quarter of the
// 16x64 gemm2 tile (4 MFMAs, B=WT2 L1-hot) and store h2 = h1 @ W2. h1 never touches HBM.
__global__ __launch_bounds__(1024) void fusedA1G2_k(const __half* __restrict__ H,
                                                    const int* __restrict__ rowbeg,
                                                    const int* __restrict__ rend,
                                                    const int* __restrict__ csr,
                                                    const float* __restrict__ dinv,
                                                    const float* __restrict__ b1,
                                                    const _Float16* __restrict__ WT2,
                                                    _Float16* __restrict__ H2, int nn) {
    constexpr int NF = 128;
    __shared__ _Float16 sh[16][136];   // 16 rows x 128 halfs, stride 136 (272B)
    int tid = threadIdx.x;
    int w = tid >> 6;
    int lane = tid & 63;
    int g = lane >> 4, t = lane & 15;
    int nid = (int)blockIdx.x * 16 + w;
    if (blockIdx.x == 0 && tid < 64)
        H2[(size_t)nn * 64 + tid] = (_Float16)0.f;   // dummy row nn for agg64 pads

    if (nid < nn) {
        float acc[8];
#pragma unroll
        for (int j = 0; j < 8; j++) acc[j] = 0.f;
        int beg = rowbeg[nid], end = rend[nid];
        int e0 = beg;
        for (; e0 + 16 <= end; e0 += 16) {
            int eb = e0 + g * 4;
            int s0 = csr[eb + 0], s1 = csr[eb + 1], s2 = csr[eb + 2], s3 = csr[eb + 3];
            HVec<4> va = *((const HVec<4>*)(H + (size_t)s0 * NF) + t);
            HVec<4> vb = *((const HVec<4>*)(H + (size_t)s1 * NF) + t);
            HVec<4> vc = *((const HVec<4>*)(H + (size_t)s2 * NF) + t);
            HVec<4> vd = *((const HVec<4>*)(H + (size_t)s3 * NF) + t);
#pragma unroll
            for (int q = 0; q < 4; q++) {
                __half2 pab = __hadd2(va.v[q], vb.v[q]);
                __half2 pcd = __hadd2(vc.v[q], vd.v[q]);
                float2 fab = __half22float2(pab);
                float2 fcd = __half22float2(pcd);
                acc[2 * q + 0] += fab.x + fcd.x;
                acc[2 * q + 1] += fab.y + fcd.y;
            }
        }
        for (; e0 < end; e0 += 4) {
            int s = csr[e0 + g];
            HVec<4> va = *((const HVec<4>*)(H + (size_t)s * NF) + t);
#pragma unroll
            for (int q = 0; q < 4; q++) {
                float2 f = __half22float2(va.v[q]);
                acc[2 * q + 0] += f.x;
                acc[2 * q + 1] += f.y;
            }
        }
#pragma unroll
        for (int j = 0; j < 8; j++) {
            acc[j] += __shfl_xor(acc[j], 16);
            acc[j] += __shfl_xor(acc[j], 32);
        }
        HVec<4> hn = *((const HVec<4>*)(H + (size_t)nid * NF) + t);
#pragma unroll
        for (int q = 0; q < 4; q++) {
            float2 f = __half22float2(hn.v[q]);
            acc[2 * q + 0] += f.x;
            acc[2 * q + 1] += f.y;
        }
        if (g == 0) {
            float dn = dinv[nid];
            float r[8];
#pragma unroll
            for (int j = 0; j < 8; j++) {
                r[j] = acc[j] * dn + b1[t * 8 + j];
                r[j] = fmaxf(r[j], 0.f);   // relu
                r[j] *= dn;                // pre-scale for agg2
            }
            HVec<4> o;
#pragma unroll
            for (int q = 0; q < 4; q++)
                o.v[q] = __floats2half2_rn(r[2 * q], r[2 * q + 1]);
            *(HVec<4>*)&sh[w][t * 8] = o;
        }
    }
    __syncthreads();
    if (w < 4) {
        // gemm2 quarter: cols [w*16, w*16+16) of the 16x64 tile
        int lr = lane & 15, kg = lane >> 4;
        half8 a[4];
#pragma unroll
        for (int ks = 0; ks < 4; ks++)
            a[ks] = *(const half8*)&sh[lr][ks * 32 + kg * 8];
        f32x4 acc2 = (f32x4){0.f, 0.f, 0.f, 0.f};
#pragma unroll
        for (int ks = 0; ks < 4; ks++) {
            half8 b = *(const half8*)(WT2 + (size_t)(w * 16 + lr) * 128 + ks * 32 + kg * 8);
            acc2 = __builtin_amdgcn_mfma_f32_16x16x32_f16(a[ks], b, acc2, 0, 0, 0);
        }
#pragma unroll
        for (int i = 0; i < 4; i++) {
            int rr = (int)blockIdx.x * 16 + kg * 4 + i;
            if (rr < nn)
                H2[(size_t)rr * 64 + w * 16 + lr] = (_Float16)acc2[i];
        }
    }
}

// ---------------- agg layer 2 (NF=64): 8-lane groups, 8 rows/instr ----------------
template <bool RELU>
__global__ __launch_bounds__(256) void agg64_k(const __half* __restrict__ H,
                                               const int* __restrict__ rowbeg,
                                               const int* __restrict__ rend,
                                               const int* __restrict__ csr,
                                               const float* __restrict__ dinv,
                                               const float* __restrict__ bias,
                                               float* __restrict__ Out, int nn) {
    constexpr int NF = 64;
    int wid = (int)((blockIdx.x * (size_t)blockDim.x + threadIdx.x) >> 6);
    if (wid >= nn) return;
    int lane = threadIdx.x & 63;
    int g = lane >> 3, t = lane & 7;
    float acc[8];
#pragma unroll
    for (int j = 0; j < 8; j++) acc[j] = 0.f;

    int beg = rowbeg[wid], end = rend[wid];
    int e0 = beg;
    for (; e0 + 16 <= end; e0 += 16) {
        int eb = e0 + g * 2;
        int s0 = csr[eb], s1 = csr[eb + 1];
        HVec<4> va = *((const HVec<4>*)(H + (size_t)s0 * NF) + t);
        HVec<4> vb = *((const HVec<4>*)(H + (size_t)s1 * NF) + t);
#pragma unroll
        for (int q = 0; q < 4; q++) {
            __half2 p = __hadd2(va.v[q], vb.v[q]);
            float2 f = __half22float2(p);
            acc[2 * q + 0] += f.x;
            acc[2 * q + 1] += f.y;
        }
    }
    for (; e0 < end; e0 += 8) {
        int s = csr[e0 + g];
        HVec<4> va = *((const HVec<4>*)(H + (size_t)s * NF) + t);
#pragma unroll
        for (int q = 0; q < 4; q++) {
            float2 f = __half22float2(va.v[q]);
            acc[2 * q + 0] += f.x;
            acc[2 * q + 1] += f.y;
        }
    }
#pragma unroll
    for (int j = 0; j < 8; j++) {
        acc[j] += __shfl_xor(acc[j], 8);
        acc[j] += __shfl_xor(acc[j], 16);
        acc[j] += __shfl_xor(acc[j], 32);
    }
    HVec<4> hn = *((const HVec<4>*)(H + (size_t)wid * NF) + t);
#pragma unroll
    for (int q = 0; q < 4; q++) {
        float2 f = __half22float2(hn.v[q]);
        acc[2 * q + 0] += f.x;
        acc[2 * q + 1] += f.y;
    }
    if (g == 0) {
        float dn = dinv[wid];
        float r[8];
#pragma unroll
        for (int j = 0; j < 8; j++) {
            r[j] = acc[j] * dn + bias[t * 8 + j];
            if (RELU) r[j] = fmaxf(r[j], 0.f);
        }
        float* op = Out + (size_t)wid * NF + t * 8;
        float4 o0, o1;
        o0.x = r[0]; o0.y = r[1]; o0.z = r[2]; o0.w = r[3];
        o1.x = r[4]; o1.y = r[5]; o1.z = r[6]; o1.w = r[7];
        *(float4*)op = o0;
        *(float4*)(op + 4) = o1;
    }
}

// ---------------- launch ----------------

extern "C" void kernel_launch(void* const* d_in, const int* in_sizes, int n_in,
                              void* d_out, int out_size, void* d_ws, size_t ws_size,
                              hipStream_t stream) {
    const float* x  = (const float*)d_in[0];
    const int* ei   = (const int*)d_in[1];
    const float* W1 = (const float*)d_in[2];
    const float* b1 = (const float*)d_in[3];
    const float* W2 = (const float*)d_in[4];
    const float* b2 = (const float*)d_in[5];
    float* out = (float*)d_out;

    const int IN = 128, HID = 128;
    int nn = in_sizes[0] / IN;     // 100000
    int ne = in_sizes[1] / 2;      // 1600000
    const int* src = ei;
    const int* dst = ei + ne;
    int nbuckets = (nn + NPB - 1) / NPB;   // 196 (<= NBK)

    char* w = (char*)d_ws;
    size_t off = 0;
    auto take = [&](size_t bytes) -> void* {
        void* p = w + off;
        off = (off + bytes + 255) & ~(size_t)255;
        return p;
    };
    int*      cursor = (int*)take(NBK * 4);
    int*      rowbeg = (int*)take((size_t)nn * 4);
    int*      rend   = (int*)take((size_t)nn * 4);
    float*    dinv   = (float*)take((size_t)nn * 4);
    int*      csr    = (int*)take((size_t)NBK * CCAP * 4);            // fixed-cap regions
    _Float16* WT1    = (_Float16*)take(128 * 128 * 2);
    _Float16* WT2    = (_Float16*)take(64 * 128 * 2);
    _Float16* h      = (_Float16*)take((size_t)(nn + 1) * HID * 2);   // layer-1 h' + dummy row
    _Float16* h2     = (_Float16*)take((size_t)(nn + 1) * 64 * 2);    // layer-2 h2' + dummy row
    int*      bucketed = (int*)h;          // reuse: 10.5MB <= 25.8MB, dead before gemm1

    (void)ws_size; (void)n_in; (void)out_size;

    int tb = 256;
    prep0_k<<<(128 * 128 + 128 * 64 + tb - 1) / tb, tb, 0, stream>>>(W1, W2, WT1, WT2, cursor);
    partA_k<<<(ne + EPB - 1) / EPB, 512, 0, stream>>>(src, dst, cursor, bucketed, ne);
    csrB_k<<<nbuckets, 1024, 0, stream>>>(bucketed, cursor, csr, rowbeg, rend, dinv, nn);

    int gblocks = ((nn + 15) / 16 + 3) / 4;   // 1 wave per 16 rows, 4 waves/block

    // layer 1 dense: h' = dinv .* (x @ W1)  [fp16 row-major]
    gemm_mfma_k<128, true, float><<<gblocks, tb, 0, stream>>>(x, WT1, dinv, h, nn);
    // fused: h1 = dinv.*relu(agg(h')+b1) (LDS only) ; h2' = h1 @ W2
    fusedA1G2_k<<<(nn + 15) / 16, 1024, 0, stream>>>(
        (const __half*)h, rowbeg, rend, csr, dinv, b1, WT2, h2, nn);
    // layer 2 aggregation: out = agg(h2') + b2  [fp32]
    agg64_k<false><<<(nn * 64 + tb - 1) / tb, tb, 0, stream>>>(
        (const __half*)h2, rowbeg, rend, csr, dinv, b2, out, nn);
}

// Round 15
// 190.914 us; speedup vs baseline: 1.6813x; 1.0330x over previous
//
#include <hip/hip_runtime.h>
#include <hip/hip_fp16.h>
#include <type_traits>

// Buckets of 512 nodes; fixed-capacity regions (mean count 8163, sigma ~90).
#define NBK 256
#define BSHIFT 9
#define NPB 512
#define BCAP 10240     // per-bucket 'bucketed' capacity
#define CCAP 12288     // per-bucket csr capacity (count + pad8 worst case fits)
#define EPB 4096       // edges per partA block

template <int N> struct alignas(4 * N) HVec { __half2 v[N]; };

typedef _Float16 half8 __attribute__((ext_vector_type(8)));
typedef float f32x4 __attribute__((ext_vector_type(4)));

// ---- prep0: zero bucket cursors + transpose W1/W2 to fp16 WT[j][k] ----
__global__ void prep0_k(const float* __restrict__ W1, const float* __restrict__ W2,
                        _Float16* __restrict__ WT1, _Float16* __restrict__ WT2,
                        int* __restrict__ cursor) {
    int i = blockIdx.x * blockDim.x + threadIdx.x;
    if (i < NBK) cursor[i] = 0;
    if (i < 128 * 128) {
        int k = i >> 7, j = i & 127;
        WT1[j * 128 + k] = (_Float16)W1[i];
    }
    int i2 = i - 128 * 128;
    if (i2 >= 0 && i2 < 128 * 64) {
        int k = i2 >> 6, j = i2 & 63;
        WT2[j * 128 + k] = (_Float16)W2[i2];
    }
}

// ---- partA: single-pass partition into fixed-capacity bucket regions ----
__global__ __launch_bounds__(512) void partA_k(const int* __restrict__ src,
                                               const int* __restrict__ dst,
                                               int* __restrict__ cursor,
                                               int* __restrict__ bucketed, int ne) {
    __shared__ int hist[NBK], gbs[NBK];
    int t = threadIdx.x;
    int e0 = blockIdx.x * EPB;
    int e1 = min(e0 + EPB, ne);
    for (int i = t; i < NBK; i += 512) hist[i] = 0;
    __syncthreads();
    int sv[EPB / 512], dv[EPB / 512], rv[EPB / 512];
#pragma unroll
    for (int k = 0; k < EPB / 512; k++) {
        int e = e0 + t + k * 512;
        int s = 0, d = -1, r = 0;
        if (e < e1) {
            s = src[e];
            d = dst[e];
            r = atomicAdd(&hist[d >> BSHIFT], 1);   // rank within block's bucket run
        }
        sv[k] = s; dv[k] = d; rv[k] = r;
    }
    __syncthreads();
    for (int i = t; i < NBK; i += 512)
        gbs[i] = hist[i] ? atomicAdd(&cursor[i], hist[i]) : 0;
    __syncthreads();
#pragma unroll
    for (int k = 0; k < EPB / 512; k++) {
        if (dv[k] >= 0) {
            int b = dv[k] >> BSHIFT;
            int q = gbs[b] + rv[k];
            if (q < BCAP)   // defensive (never expected)
                bucketed[(size_t)b * BCAP + q] = ((dv[k] & (NPB - 1)) << 17) | sv[k];
        }
    }
}

// ---- csrB: per-bucket CSR finalize, pad8 (dummy src = nn -> zero row) ----
__global__ __launch_bounds__(1024) void csrB_k(const int* __restrict__ bucketed,
                                               const int* __restrict__ cursor,
                                               int* __restrict__ csr,
                                               int* __restrict__ rowbeg,
                                               int* __restrict__ rend,
                                               float* __restrict__ dinv, int nn) {
    __shared__ int cnt[NPB], ofs[NPB], exs[NPB];
    int t = threadIdx.x;
    int b = blockIdx.x;
    int m = min(cursor[b], BCAP);
    const int* bk = bucketed + (size_t)b * BCAP;
    int cbase = b * CCAP;
    if (t < NPB) cnt[t] = 0;
    __syncthreads();
    int rk[(BCAP + 1023) / 1024];
    int nit = 0;
    for (int i = t; i < m; i += 1024)
        rk[nit++] = atomicAdd(&cnt[bk[i] >> 17], 1);   // rank within node
    __syncthreads();
    int v = 0, pv = 0;
    if (t < NPB) { v = cnt[t]; pv = (v + 7) & ~7; ofs[t] = pv; }
    __syncthreads();
    for (int d = 1; d < NPB; d <<= 1) {
        int u = 0;
        if (t < NPB && t >= d) u = ofs[t - d];
        __syncthreads();
        if (t < NPB) ofs[t] += u;
        __syncthreads();
    }
    if (t < NPB) {
        int ex = ofs[t] - pv;
        exs[t] = ex;
        int node = b * NPB + t;
        if (node < nn) {
            rowbeg[node] = cbase + ex;
            rend[node]   = cbase + ex + pv;
            dinv[node] = rsqrtf((float)(v + 1));   // +1 self-loop
        }
    }
    __syncthreads();
    nit = 0;
    for (int i = t; i < m; i += 1024) {
        int e = bk[i];
        csr[cbase + exs[e >> 17] + rk[nit++]] = e & 0x1FFFF;
    }
    if (t < NPB) {
        int ex = exs[t];
        for (int k = v; k < pv; k++) csr[cbase + ex + k] = nn;   // pads, disjoint addrs
    }
}

// ---------------- MFMA dense transform (layer 1): h' = dinv .* (X @ W1), fp16 ----------------
template <int NO, bool SCALE, typename XT>
__global__ __launch_bounds__(256) void gemm_mfma_k(const XT* __restrict__ X,
                                                   const _Float16* __restrict__ WT,
                                                   const float* __restrict__ dinv,
                                                   _Float16* __restrict__ H, int nrows) {
    constexpr int K = 128;
    constexpr int NCT = NO / 16;
    if (blockIdx.x == 0 && threadIdx.x < NO)
        H[(size_t)nrows * NO + threadIdx.x] = (_Float16)0.f;   // dummy row nn = 0
    int wv = (int)((blockIdx.x * (size_t)blockDim.x + threadIdx.x) >> 6);
    int r0 = wv * 16;
    if (r0 >= nrows) return;
    int lane = threadIdx.x & 63;
    int lr = lane & 15;          // A-row / D-col
    int kg = lane >> 4;          // k-group
    int rg = r0 + lr;
    if (rg >= nrows) rg = nrows - 1;   // clamp (stores are guarded)

    half8 a[4];
    if constexpr (std::is_same<XT, float>::value) {
#pragma unroll
        for (int ks = 0; ks < 4; ks++) {
            const float* px = X + (size_t)rg * K + ks * 32 + kg * 8;
            float4 x0 = *(const float4*)px;
            float4 x1 = *(const float4*)(px + 4);
            half8 vv;
            vv[0] = (_Float16)x0.x; vv[1] = (_Float16)x0.y;
            vv[2] = (_Float16)x0.z; vv[3] = (_Float16)x0.w;
            vv[4] = (_Float16)x1.x; vv[5] = (_Float16)x1.y;
            vv[6] = (_Float16)x1.z; vv[7] = (_Float16)x1.w;
            a[ks] = vv;
        }
    } else {
#pragma unroll
        for (int ks = 0; ks < 4; ks++)
            a[ks] = *(const half8*)(X + (size_t)rg * K + ks * 32 + kg * 8);
    }

    f32x4 acc[NCT];
#pragma unroll
    for (int ct = 0; ct < NCT; ct++) acc[ct] = (f32x4){0.f, 0.f, 0.f, 0.f};
#pragma unroll
    for (int ct = 0; ct < NCT; ct++) {
#pragma unroll
        for (int ks = 0; ks < 4; ks++) {
            half8 b = *(const half8*)(WT + (size_t)(ct * 16 + lr) * K + ks * 32 + kg * 8);
            acc[ct] = __builtin_amdgcn_mfma_f32_16x16x32_f16(a[ks], b, acc[ct], 0, 0, 0);
        }
    }
#pragma unroll
    for (int i = 0; i < 4; i++) {
        int rr = r0 + kg * 4 + i;
        if (rr < nrows) {
            float s = SCALE ? dinv[rr] : 1.f;
            _Float16* hp = H + (size_t)rr * NO + lr;
#pragma unroll
            for (int ct = 0; ct < NCT; ct++)
                hp[ct * 16] = (_Float16)(acc[ct][i] * s);
        }
    }
}

// ---------------- FUSED agg1 + gemm2 (v2: imbalance-amortized) ----------------
// Block = 256 threads = 4 waves; each wave aggregates 4 nodes SEQUENTIALLY (wave time
// ~ sum of 4 degrees -> sigma 12% vs 25% per-node; barrier couples only 4 waves).
// h1 rows parked in LDS sh[16][136] (2-way bank alias, free). Barrier. Wave w computes
// col-quarter w of the 16x64 gemm2 tile (4 MFMAs, B=WT2 L1-hot). h1 never touches HBM.
__global__ __launch_bounds__(256) void fusedA1G2_k(const __half* __restrict__ H,
                                                   const int* __restrict__ rowbeg,
                                                   const int* __restrict__ rend,
                                                   const int* __restrict__ csr,
                                                   const float* __restrict__ dinv,
                                                   const float* __restrict__ b1,
                                                   const _Float16* __restrict__ WT2,
                                                   _Float16* __restrict__ H2, int nn) {
    constexpr int NF = 128;
    __shared__ _Float16 sh[16][136];   // 16 rows x 128 halfs, stride 136 (272B)
    int tid = threadIdx.x;
    int w = tid >> 6;
    int lane = tid & 63;
    int g = lane >> 4, t = lane & 15;
    int base = (int)blockIdx.x * 16;
    if (blockIdx.x == 0 && tid < 64)
        H2[(size_t)nn * 64 + tid] = (_Float16)0.f;   // dummy row nn for agg64 pads

#pragma unroll 1
    for (int s = 0; s < 4; s++) {
        int nid = base + w * 4 + s;
        if (nid >= nn) break;          // wave-uniform
        float acc[8];
#pragma unroll
        for (int j = 0; j < 8; j++) acc[j] = 0.f;
        int beg = rowbeg[nid], end = rend[nid];
        int e0 = beg;
        for (; e0 + 16 <= end; e0 += 16) {
            int eb = e0 + g * 4;
            int s0 = csr[eb + 0], s1 = csr[eb + 1], s2 = csr[eb + 2], s3 = csr[eb + 3];
            HVec<4> va = *((const HVec<4>*)(H + (size_t)s0 * NF) + t);
            HVec<4> vb = *((const HVec<4>*)(H + (size_t)s1 * NF) + t);
            HVec<4> vc = *((const HVec<4>*)(H + (size_t)s2 * NF) + t);
            HVec<4> vd = *((const HVec<4>*)(H + (size_t)s3 * NF) + t);
#pragma unroll
            for (int q = 0; q < 4; q++) {
                __half2 pab = __hadd2(va.v[q], vb.v[q]);
                __half2 pcd = __hadd2(vc.v[q], vd.v[q]);
                float2 fab = __half22float2(pab);
                float2 fcd = __half22float2(pcd);
                acc[2 * q + 0] += fab.x + fcd.x;
                acc[2 * q + 1] += fab.y + fcd.y;
            }
        }
        for (; e0 < end; e0 += 4) {
            int sx = csr[e0 + g];
            HVec<4> va = *((const HVec<4>*)(H + (size_t)sx * NF) + t);
#pragma unroll
            for (int q = 0; q < 4; q++) {
                float2 f = __half22float2(va.v[q]);
                acc[2 * q + 0] += f.x;
                acc[2 * q + 1] += f.y;
            }
        }
#pragma unroll
        for (int j = 0; j < 8; j++) {
            acc[j] += __shfl_xor(acc[j], 16);
            acc[j] += __shfl_xor(acc[j], 32);
        }
        HVec<4> hn = *((const HVec<4>*)(H + (size_t)nid * NF) + t);
#pragma unroll
        for (int q = 0; q < 4; q++) {
            float2 f = __half22float2(hn.v[q]);
            acc[2 * q + 0] += f.x;
            acc[2 * q + 1] += f.y;
        }
        if (g == 0) {
            float dn = dinv[nid];
            float r[8];
#pragma unroll
            for (int j = 0; j < 8; j++) {
                r[j] = acc[j] * dn + b1[t * 8 + j];
                r[j] = fmaxf(r[j], 0.f);   // relu
                r[j] *= dn;                // pre-scale for agg2
            }
            HVec<4> o;
#pragma unroll
            for (int q = 0; q < 4; q++)
                o.v[q] = __floats2half2_rn(r[2 * q], r[2 * q + 1]);
            *(HVec<4>*)&sh[w * 4 + s][t * 8] = o;
        }
    }
    __syncthreads();
    // gemm2 quarter: wave w computes cols [w*16, w*16+16) of the 16x64 tile
    {
        int lr = lane & 15, kg = lane >> 4;
        half8 a[4];
#pragma unroll
        for (int ks = 0; ks < 4; ks++)
            a[ks] = *(const half8*)&sh[lr][ks * 32 + kg * 8];
        f32x4 acc2 = (f32x4){0.f, 0.f, 0.f, 0.f};
#pragma unroll
        for (int ks = 0; ks < 4; ks++) {
            half8 b = *(const half8*)(WT2 + (size_t)(w * 16 + lr) * 128 + ks * 32 + kg * 8);
            acc2 = __builtin_amdgcn_mfma_f32_16x16x32_f16(a[ks], b, acc2, 0, 0, 0);
        }
#pragma unroll
        for (int i = 0; i < 4; i++) {
            int rr = base + kg * 4 + i;
            if (rr < nn)
                H2[(size_t)rr * 64 + w * 16 + lr] = (_Float16)acc2[i];
        }
    }
}

// ---------------- agg layer 2 (NF=64): 8-lane groups, 8 rows/instr ----------------
template <bool RELU>
__global__ __launch_bounds__(256) void agg64_k(const __half* __restrict__ H,
                                               const int* __restrict__ rowbeg,
                                               const int* __restrict__ rend,
                                               const int* __restrict__ csr,
                                               const float* __restrict__ dinv,
                                               const float* __restrict__ bias,
                                               float* __restrict__ Out, int nn) {
    constexpr int NF = 64;
    int wid = (int)((blockIdx.x * (size_t)blockDim.x + threadIdx.x) >> 6);
    if (wid >= nn) return;
    int lane = threadIdx.x & 63;
    int g = lane >> 3, t = lane & 7;
    float acc[8];
#pragma unroll
    for (int j = 0; j < 8; j++) acc[j] = 0.f;

    int beg = rowbeg[wid], end = rend[wid];
    int e0 = beg;
    for (; e0 + 16 <= end; e0 += 16) {
        int eb = e0 + g * 2;
        int s0 = csr[eb], s1 = csr[eb + 1];
        HVec<4> va = *((const HVec<4>*)(H + (size_t)s0 * NF) + t);
        HVec<4> vb = *((const HVec<4>*)(H + (size_t)s1 * NF) + t);
#pragma unroll
        for (int q = 0; q < 4; q++) {
            __half2 p = __hadd2(va.v[q], vb.v[q]);
            float2 f = __half22float2(p);
            acc[2 * q + 0] += f.x;
            acc[2 * q + 1] += f.y;
        }
    }
    for (; e0 < end; e0 += 8) {
        int s = csr[e0 + g];
        HVec<4> va = *((const HVec<4>*)(H + (size_t)s * NF) + t);
#pragma unroll
        for (int q = 0; q < 4; q++) {
            float2 f = __half22float2(va.v[q]);
            acc[2 * q + 0] += f.x;
            acc[2 * q + 1] += f.y;
        }
    }
#pragma unroll
    for (int j = 0; j < 8; j++) {
        acc[j] += __shfl_xor(acc[j], 8);
        acc[j] += __shfl_xor(acc[j], 16);
        acc[j] += __shfl_xor(acc[j], 32);
    }
    HVec<4> hn = *((const HVec<4>*)(H + (size_t)wid * NF) + t);
#pragma unroll
    for (int q = 0; q < 4; q++) {
        float2 f = __half22float2(hn.v[q]);
        acc[2 * q + 0] += f.x;
        acc[2 * q + 1] += f.y;
    }
    if (g == 0) {
        float dn = dinv[wid];
        float r[8];
#pragma unroll
        for (int j = 0; j < 8; j++) {
            r[j] = acc[j] * dn + bias[t * 8 + j];
            if (RELU) r[j] = fmaxf(r[j], 0.f);
        }
        float* op = Out + (size_t)wid * NF + t * 8;
        float4 o0, o1;
        o0.x = r[0]; o0.y = r[1]; o0.z = r[2]; o0.w = r[3];
        o1.x = r[4]; o1.y = r[5]; o1.z = r[6]; o1.w = r[7];
        *(float4*)op = o0;
        *(float4*)(op + 4) = o1;
    }
}

// ---------------- launch ----------------

extern "C" void kernel_launch(void* const* d_in, const int* in_sizes, int n_in,
                              void* d_out, int out_size, void* d_ws, size_t ws_size,
                              hipStream_t stream) {
    const float* x  = (const float*)d_in[0];
    const int* ei   = (const int*)d_in[1];
    const float* W1 = (const float*)d_in[2];
    const float* b1 = (const float*)d_in[3];
    const float* W2 = (const float*)d_in[4];
    const float* b2 = (const float*)d_in[5];
    float* out = (float*)d_out;

    const int IN = 128, HID = 128;
    int nn = in_sizes[0] / IN;     // 100000
    int ne = in_sizes[1] / 2;      // 1600000
    const int* src = ei;
    const int* dst = ei + ne;
    int nbuckets = (nn + NPB - 1) / NPB;   // 196 (<= NBK)

    char* w = (char*)d_ws;
    size_t off = 0;
    auto take = [&](size_t bytes) -> void* {
        void* p = w + off;
        off = (off + bytes + 255) & ~(size_t)255;
        return p;
    };
    int*      cursor = (int*)take(NBK * 4);
    int*      rowbeg = (int*)take((size_t)nn * 4);
    int*      rend   = (int*)take((size_t)nn * 4);
    float*    dinv   = (float*)take((size_t)nn * 4);
    int*      csr    = (int*)take((size_t)NBK * CCAP * 4);            // fixed-cap regions
    _Float16* WT1    = (_Float16*)take(128 * 128 * 2);
    _Float16* WT2    = (_Float16*)take(64 * 128 * 2);
    _Float16* h      = (_Float16*)take((size_t)(nn + 1) * HID * 2);   // layer-1 h' + dummy row
    _Float16* h2     = (_Float16*)take((size_t)(nn + 1) * 64 * 2);    // layer-2 h2' + dummy row
    int*      bucketed = (int*)h;          // reuse: 10.5MB <= 25.8MB, dead before gemm1

    (void)ws_size; (void)n_in; (void)out_size;

    int tb = 256;
    prep0_k<<<(128 * 128 + 128 * 64 + tb - 1) / tb, tb, 0, stream>>>(W1, W2, WT1, WT2, cursor);
    partA_k<<<(ne + EPB - 1) / EPB, 512, 0, stream>>>(src, dst, cursor, bucketed, ne);
    csrB_k<<<nbuckets, 1024, 0, stream>>>(bucketed, cursor, csr, rowbeg, rend, dinv, nn);

    int gblocks = ((nn + 15) / 16 + 3) / 4;   // 1 wave per 16 rows, 4 waves/block

    // layer 1 dense: h' = dinv .* (x @ W1)  [fp16 row-major]
    gemm_mfma_k<128, true, float><<<gblocks, tb, 0, stream>>>(x, WT1, dinv, h, nn);
    // fused: h1 = dinv.*relu(agg(h')+b1) (LDS only) ; h2' = h1 @ W2
    fusedA1G2_k<<<(nn + 15) / 16, tb, 0, stream>>>(
        (const __half*)h, rowbeg, rend, csr, dinv, b1, WT2, h2, nn);
    // layer 2 aggregation: out = agg(h2') + b2  [fp32]
    agg64_k<false><<<(nn * 64 + tb - 1) / tb, tb, 0, stream>>>(
        (const __half*)h2, rowbeg, rend, csr, dinv, b2, out, nn);
}